// Round 4
// baseline (989.266 us; speedup 1.0000x reference)
//
#include <hip/hip_runtime.h>
#include <hip/hip_bf16.h>

// Problem constants (GAT_18176301597437)
#define N_NODES 4096
#define F_IN    256
#define KH      8
#define FPH     64
#define KF      512          // KH*FPH
#define NEG_SLOPE 0.2f

// ---------- helpers ----------
__device__ __forceinline__ float bf2f(unsigned short u) {
    unsigned v = ((unsigned)u) << 16;
    float f; __builtin_memcpy(&f, &v, 4);
    return f;
}
__device__ __forceinline__ unsigned short f2bf(float f) {
    __hip_bfloat16 h = __float2bfloat16(f);   // round-to-nearest-even
    unsigned short u; __builtin_memcpy(&u, &h, 2);
    return u;
}

// ---------- Kernel 0: runtime dtype detection (insurance; expect fp32/int32) ----------
__global__ void detect_kernel(const unsigned* __restrict__ xw,
                              const unsigned* __restrict__ mw,
                              int* __restrict__ flags) {
  if (threadIdx.x != 0 || blockIdx.x != 0) return;
  int ok_lo = 0;
  for (int i = 0; i < 64; ++i) {
    const unsigned w = xw[i];
    const float lo = bf2f((unsigned short)(w & 0xFFFF));
    const float a = fabsf(lo);
    if (lo == 0.f || (a > 1e-8f && a < 100.f)) ok_lo++;
  }
  flags[0] = (ok_lo >= 48) ? 1 : 0;   // 1 = packed bf16, 0 = fp32

  bool all01 = true;
  for (int i = 0; i < 64; ++i) if (mw[i] > 1u) { all01 = false; break; }
  int mtype = 0;                       // 0 = int32 {0,1}
  if (!all01) {
    bool bytes01 = true;
    for (int i = 0; i < 64; ++i) {
      const unsigned v = mw[i];
      if (((v & 0xFFu) > 1u) || (((v >> 8) & 0xFFu) > 1u) ||
          (((v >> 16) & 0xFFu) > 1u) || ((v >> 24) > 1u)) { bytes01 = false; break; }
    }
    mtype = bytes01 ? 1 : 2;           // 1 = bytes, 2 = 16-bit
  }
  flags[1] = mtype;
}

// ---------- Kernel 0b: convert an input tensor to canonical fp32 ----------
__global__ __launch_bounds__(256) void convert_in(
    const void* __restrict__ src, float* __restrict__ dst, int n,
    const int* __restrict__ flags) {
  const int i = blockIdx.x * 256 + threadIdx.x;
  if (i >= n) return;
  if (flags[0]) dst[i] = bf2f(((const unsigned short*)src)[i]);
  else          dst[i] = ((const float*)src)[i];
}

// ---------- Kernel 0c: pack mask into bits (bit i = element i) ----------
__global__ __launch_bounds__(256) void mask_pack(
    const void* __restrict__ mask, const int* __restrict__ flags,
    unsigned long long* __restrict__ bits) {
  const size_t idx = (size_t)blockIdx.x * 256 + threadIdx.x;
  const int mtype = flags[1];
  bool pred;
  if (mtype == 0)      pred = ((const int*)mask)[idx] != 0;
  else if (mtype == 1) pred = ((const unsigned char*)mask)[idx] != 0;
  else                 pred = (((const unsigned short*)mask)[idx] & 0x7FFF) != 0;
  const unsigned long long b = __ballot(pred);
  if ((threadIdx.x & 63) == 0) bits[idx >> 6] = b;
}

// ---------- Kernel A: xe = x @ W_w^T + W_b (fp32 in, fp32 + bf16 out) ----------
__global__ __launch_bounds__(256) void xe_gemm(
    const float* __restrict__ x,
    const float* __restrict__ Ww,
    const float* __restrict__ Wb,
    float* __restrict__ xe_f,
    unsigned short* __restrict__ xe_b) {
  __shared__ float As[64][33];
  __shared__ float Bs[64][33];
  const int tid = threadIdx.x;
  const int n0 = blockIdx.x * 64;
  const int j0 = blockIdx.y * 64;
  const int lr = tid >> 2;          // 0..63
  const int lc = (tid & 3) * 8;     // 0,8,16,24
  const int ty = tid >> 4;
  const int tx = tid & 15;
  float c[4][4];
  #pragma unroll
  for (int i = 0; i < 4; ++i)
    #pragma unroll
    for (int j = 0; j < 4; ++j) c[i][j] = 0.f;

  for (int f0 = 0; f0 < F_IN; f0 += 32) {
    const float* ap = x  + (size_t)(n0 + lr) * F_IN + f0 + lc;
    const float* bp = Ww + (size_t)(j0 + lr) * F_IN + f0 + lc;
    const float4 a0 = *(const float4*)ap;
    const float4 a1 = *(const float4*)(ap + 4);
    const float4 b0 = *(const float4*)bp;
    const float4 b1 = *(const float4*)(bp + 4);
    __syncthreads();
    As[lr][lc + 0] = a0.x; As[lr][lc + 1] = a0.y;
    As[lr][lc + 2] = a0.z; As[lr][lc + 3] = a0.w;
    As[lr][lc + 4] = a1.x; As[lr][lc + 5] = a1.y;
    As[lr][lc + 6] = a1.z; As[lr][lc + 7] = a1.w;
    Bs[lr][lc + 0] = b0.x; Bs[lr][lc + 1] = b0.y;
    Bs[lr][lc + 2] = b0.z; Bs[lr][lc + 3] = b0.w;
    Bs[lr][lc + 4] = b1.x; Bs[lr][lc + 5] = b1.y;
    Bs[lr][lc + 6] = b1.z; Bs[lr][lc + 7] = b1.w;
    __syncthreads();
    #pragma unroll
    for (int kk = 0; kk < 32; ++kk) {
      float av[4], bv[4];
      #pragma unroll
      for (int i = 0; i < 4; ++i) av[i] = As[ty * 4 + i][kk];
      #pragma unroll
      for (int j = 0; j < 4; ++j) bv[j] = Bs[tx * 4 + j][kk];
      #pragma unroll
      for (int i = 0; i < 4; ++i)
        #pragma unroll
        for (int j = 0; j < 4; ++j) c[i][j] = fmaf(av[i], bv[j], c[i][j]);
    }
  }
  #pragma unroll
  for (int i = 0; i < 4; ++i) {
    const int n = n0 + ty * 4 + i;
    #pragma unroll
    for (int j = 0; j < 4; ++j) {
      const int col = j0 + tx * 4 + j;
      const float v = c[i][j] + Wb[col];
      xe_f[(size_t)n * KF + col] = v;
      xe_b[(size_t)n * KF + col] = f2bf(v);
    }
  }
}

// ---------- Kernel B: hl[k,n], hr[k,n] ----------
__global__ __launch_bounds__(512) void hlr_kernel(
    const float* __restrict__ xe_f,
    const float* __restrict__ al,
    const float* __restrict__ ar,
    float* __restrict__ hl, float* __restrict__ hr) {
  const int n = blockIdx.x;
  const int t = threadIdx.x;        // t = k*64 + f
  const int k = t >> 6;
  const int f = t & 63;
  const float v = xe_f[(size_t)n * KF + t];
  float sl = v * al[t];
  float sr = v * ar[t];
  #pragma unroll
  for (int o = 32; o > 0; o >>= 1) {
    sl += __shfl_down(sl, o);
    sr += __shfl_down(sr, o);
  }
  if (f == 0) {
    hl[k * N_NODES + n] = sl;
    hr[k * N_NODES + n] = sr;
  }
}

// ---------- Kernel B2: per-head global max of hr ----------
__global__ __launch_bounds__(256) void hrmax_kernel(
    const float* __restrict__ hr, float* __restrict__ hrmax) {
  __shared__ float red[256];
  const int k = blockIdx.x;
  const int t = threadIdx.x;
  float m = -1e30f;
  for (int i = t; i < N_NODES; i += 256) m = fmaxf(m, hr[k * N_NODES + i]);
  red[t] = m;
  __syncthreads();
  for (int s = 128; s > 0; s >>= 1) {
    if (t < s) red[t] = fmaxf(red[t], red[t + s]);
    __syncthreads();
  }
  if (t == 0) hrmax[k] = red[0];
}

// ---------- Kernel C: mask passthrough -> fp32 {0,1}. Runs LAST. ----------
__global__ __launch_bounds__(256) void mask_copy(
    const void* __restrict__ mask, const int* __restrict__ flags,
    float* __restrict__ outm) {
  const size_t i4 = (size_t)blockIdx.x * 256 + threadIdx.x;  // 4 elems/thread
  const int mtype = flags[1];
  float4 o;
  if (mtype == 0) {
    const int4 mv = ((const int4*)mask)[i4];
    o.x = mv.x ? 1.f : 0.f; o.y = mv.y ? 1.f : 0.f;
    o.z = mv.z ? 1.f : 0.f; o.w = mv.w ? 1.f : 0.f;
  } else if (mtype == 1) {
    const unsigned mv = ((const unsigned*)mask)[i4];
    o.x = (mv & 0xFFu)         ? 1.f : 0.f;
    o.y = ((mv >> 8) & 0xFFu)  ? 1.f : 0.f;
    o.z = ((mv >> 16) & 0xFFu) ? 1.f : 0.f;
    o.w = (mv >> 24)           ? 1.f : 0.f;
  } else {
    const ushort4 mv = ((const ushort4*)mask)[i4];
    o.x = (mv.x & 0x7FFF) ? 1.f : 0.f; o.y = (mv.y & 0x7FFF) ? 1.f : 0.f;
    o.z = (mv.z & 0x7FFF) ? 1.f : 0.f; o.w = (mv.w & 0x7FFF) ? 1.f : 0.f;
  }
  ((float4*)outm)[i4] = o;
}

// ---------- Kernel D: fused masked-softmax attention + PV + double ELU ----------
// One block = 16 rows, all 8 heads. 512 threads = 8 waves.
__global__ __launch_bounds__(512) void gat_attn(
    const unsigned long long* __restrict__ mbits,
    const float* __restrict__ hl,
    const float* __restrict__ hr,
    const float* __restrict__ hrmax,
    const unsigned short* __restrict__ xe_b,
    float* __restrict__ out) {
  __shared__ float w_lds[KH][16][64];   // 32 KB
  __shared__ float hl_s[KH][16];
  __shared__ float M_s[KH][16];
  __shared__ float denom_s[KH][16];
  const int t = threadIdx.x;
  const int wave = t >> 6;              // 0..7
  const int lane = t & 63;
  const int n0 = blockIdx.x * 16;

  if (t < 128) {
    const int k = t >> 4, r = t & 15;
    const float h = hl[k * N_NODES + n0 + r];
    hl_s[k][r] = h;
    const float s = h + hrmax[k];
    M_s[k][r] = fmaxf(s, NEG_SLOPE * s);   // lrelu; >= every score in the row
  }
  float acc[16];
  #pragma unroll
  for (int r = 0; r < 16; ++r) acc[r] = 0.f;
  float dp[KH][2];
  #pragma unroll
  for (int k = 0; k < KH; ++k) { dp[k][0] = 0.f; dp[k][1] = 0.f; }

  const int kq = wave;                  // stage-2 head
  const int f = lane;
  const unsigned short* xcol = xe_b + kq * 64 + f;
  const unsigned long long* mrow0 = mbits + ((size_t)(n0 + wave)     << 6);
  const unsigned long long* mrow1 = mbits + ((size_t)(n0 + wave + 8) << 6);
  __syncthreads();

  for (int base = 0; base < N_NODES; base += 64) {
    // ---- stage 1: attention weights for this m-chunk ----
    const int m = base + lane;
    const unsigned long long w0b = mrow0[base >> 6];
    const unsigned long long w1b = mrow1[base >> 6];
    const bool mv0 = (w0b >> lane) & 1ull;
    const bool mv1 = (w1b >> lane) & 1ull;
    #pragma unroll
    for (int k = 0; k < KH; ++k) {
      const float hrv = hr[k * N_NODES + m];
      float s0 = hl_s[k][wave] + hrv;
      s0 = fmaxf(s0, NEG_SLOPE * s0);
      const float w0 = mv0 ? __expf(s0 - M_s[k][wave]) : 0.f;
      w_lds[k][wave][lane] = w0;
      dp[k][0] += w0;
      float s1 = hl_s[k][wave + 8] + hrv;
      s1 = fmaxf(s1, NEG_SLOPE * s1);
      const float w1 = mv1 ? __expf(s1 - M_s[k][wave + 8]) : 0.f;
      w_lds[k][wave + 8][lane] = w1;
      dp[k][1] += w1;
    }
    __syncthreads();
    // ---- stage 2: rank-64 PV update ----
    for (int mmb = 0; mmb < 64; mmb += 4) {
      const float xv0 = bf2f(xcol[(size_t)(base + mmb + 0) * KF]);
      const float xv1 = bf2f(xcol[(size_t)(base + mmb + 1) * KF]);
      const float xv2 = bf2f(xcol[(size_t)(base + mmb + 2) * KF]);
      const float xv3 = bf2f(xcol[(size_t)(base + mmb + 3) * KF]);
      #pragma unroll
      for (int r = 0; r < 16; ++r) {
        const float4 w4 = *(const float4*)(&w_lds[kq][r][mmb]);  // broadcast read
        float a = acc[r];
        a = fmaf(w4.x, xv0, a);
        a = fmaf(w4.y, xv1, a);
        a = fmaf(w4.z, xv2, a);
        a = fmaf(w4.w, xv3, a);
        acc[r] = a;
      }
    }
    __syncthreads();
  }

  // ---- reduce softmax denominators ----
  #pragma unroll
  for (int k = 0; k < KH; ++k) {
    #pragma unroll
    for (int j = 0; j < 2; ++j) {
      float v = dp[k][j];
      #pragma unroll
      for (int o = 32; o > 0; o >>= 1) v += __shfl_down(v, o);
      if (lane == 0) denom_s[k][wave + j * 8] = v;
    }
  }
  __syncthreads();

  // ---- epilogue: normalize, elu(elu(.)), store fp32 ----
  #pragma unroll
  for (int r = 0; r < 16; ++r) {
    float v = acc[r] / denom_s[kq][r];
    v = (v > 0.f) ? v : (__expf(v) - 1.f);
    v = (v > 0.f) ? v : (__expf(v) - 1.f);
    out[(size_t)(n0 + r) * KF + kq * 64 + f] = v;
  }
}

// ---------- launcher ----------
extern "C" void kernel_launch(void* const* d_in, const int* in_sizes, int n_in,
                              void* d_out, int out_size, void* d_ws, size_t ws_size,
                              hipStream_t stream) {
  const void* x    = d_in[0];   // (4096,256)  fp32 (runtime-verified)
  const void* Ww   = d_in[1];   // (512,256)
  const void* Wb   = d_in[2];   // (512,)
  const void* al   = d_in[3];   // (1,8,64)
  const void* ar   = d_in[4];   // (1,8,64)
  const void* mask = d_in[5];   // (1,4096,4096) int32/bytes/16-bit (detected)

  float* out      = (float*)d_out;                    // (4096,512) fp32, 8 MB
  float* out_mask = out + (size_t)N_NODES * KF;       // (1,4096,4096) fp32, 64 MB

  // ---- scratch inside the 64 MB mask-passthrough region of d_out ----
  // mask_copy runs LAST and overwrites it with the real mask output.
  char* scratch = (char*)out_mask;
  float*          xe_f = (float*)scratch;                           // 8 MB @ 0
  unsigned short* xe_b = (unsigned short*)(scratch + (8u << 20));   // 4 MB @ 8M
  float*          hl   = (float*)(scratch + (12u << 20));           // 128 KB
  float*          hr   = hl + KH * N_NODES;                         // 128 KB
  float*          hrmx = hr + KH * N_NODES;                         // 32 B
  float*          x_f  = (float*)(scratch + (13u << 20));           // 4 MB
  float*          Ww_f = (float*)(scratch + (17u << 20));           // 512 KB
  float*          Wb_f = (float*)(scratch + (17u << 20) + (640u << 10)); // 2 KB
  float*          al_f = Wb_f + 512;
  float*          ar_f = al_f + 512;
  int*            flags= (int*)(ar_f + 512);
  unsigned long long* mbits = (unsigned long long*)(scratch + (18u << 20)); // 2 MB
  // top of use: 20 MB < 64 MB available

  // 0: detect dtypes
  detect_kernel<<<1, 64, 0, stream>>>((const unsigned*)x, (const unsigned*)mask, flags);

  // 0b: canonicalize float inputs to fp32
  convert_in<<<4096, 256, 0, stream>>>(x,  x_f,  N_NODES * F_IN, flags);
  convert_in<<<512, 256, 0, stream>>>(Ww, Ww_f, KF * F_IN, flags);
  convert_in<<<2, 256, 0, stream>>>(Wb, Wb_f, KF, flags);
  convert_in<<<2, 256, 0, stream>>>(al, al_f, KF, flags);
  convert_in<<<2, 256, 0, stream>>>(ar, ar_f, KF, flags);

  // 0c: bit-pack the mask
  mask_pack<<<(N_NODES * (size_t)N_NODES) / 256, 256, 0, stream>>>(mask, flags, mbits);

  // A: xe = x @ W^T + b
  dim3 ga(N_NODES / 64, KF / 64);
  xe_gemm<<<ga, 256, 0, stream>>>(x_f, Ww_f, Wb_f, xe_f, xe_b);

  // B: hl, hr
  hlr_kernel<<<N_NODES, 512, 0, stream>>>(xe_f, al_f, ar_f, hl, hr);

  // B2: per-head hr max (softmax shift bound)
  hrmax_kernel<<<KH, 256, 0, stream>>>(hr, hrmx);

  // D: fused attention (consumes all scratch)
  gat_attn<<<N_NODES / 16, 512, 0, stream>>>(mbits, hl, hr, hrmx, xe_b, out);

  // C: mask passthrough — LAST, overwrites the scratch region with real output
  mask_copy<<<(N_NODES * (size_t)N_NODES) / (4 * 256), 256, 0, stream>>>(mask, flags, out_mask);
}

// Round 5
// 418.609 us; speedup vs baseline: 2.3632x; 2.3632x over previous
//
#include <hip/hip_runtime.h>
#include <hip/hip_bf16.h>

// Problem constants (GAT_18176301597437)
#define N_NODES 4096
#define F_IN    256
#define KH      8
#define FPH     64
#define KF      512          // KH*FPH
#define NEG_SLOPE 0.2f

typedef __attribute__((ext_vector_type(8))) short short8;   // 8 bf16 = 4 VGPRs
typedef __attribute__((ext_vector_type(4))) float floatx4;  // MFMA C/D

// ---------- helpers ----------
__device__ __forceinline__ float bf2f(unsigned short u) {
    unsigned v = ((unsigned)u) << 16;
    float f; __builtin_memcpy(&f, &v, 4);
    return f;
}
__device__ __forceinline__ unsigned short f2bf(float f) {
    __hip_bfloat16 h = __float2bfloat16(f);   // round-to-nearest-even
    unsigned short u; __builtin_memcpy(&u, &h, 2);
    return u;
}

// ---------- Kernel 0: runtime dtype detection (insurance; expect fp32/int32) ----------
__global__ void detect_kernel(const unsigned* __restrict__ xw,
                              const unsigned* __restrict__ mw,
                              int* __restrict__ flags) {
  if (threadIdx.x != 0 || blockIdx.x != 0) return;
  int ok_lo = 0;
  for (int i = 0; i < 64; ++i) {
    const unsigned w = xw[i];
    const float lo = bf2f((unsigned short)(w & 0xFFFF));
    const float a = fabsf(lo);
    if (lo == 0.f || (a > 1e-8f && a < 100.f)) ok_lo++;
  }
  flags[0] = (ok_lo >= 48) ? 1 : 0;   // 1 = packed bf16, 0 = fp32

  bool all01 = true;
  for (int i = 0; i < 64; ++i) if (mw[i] > 1u) { all01 = false; break; }
  int mtype = 0;                       // 0 = int32 {0,1}
  if (!all01) {
    bool bytes01 = true;
    for (int i = 0; i < 64; ++i) {
      const unsigned v = mw[i];
      if (((v & 0xFFu) > 1u) || (((v >> 8) & 0xFFu) > 1u) ||
          (((v >> 16) & 0xFFu) > 1u) || ((v >> 24) > 1u)) { bytes01 = false; break; }
    }
    mtype = bytes01 ? 1 : 2;           // 1 = bytes, 2 = 16-bit
  }
  flags[1] = mtype;
}

// ---------- Kernel 0b: convert an input tensor to canonical fp32 ----------
__global__ __launch_bounds__(256) void convert_in(
    const void* __restrict__ src, float* __restrict__ dst, int n,
    const int* __restrict__ flags) {
  const int i = blockIdx.x * 256 + threadIdx.x;
  if (i >= n) return;
  if (flags[0]) dst[i] = bf2f(((const unsigned short*)src)[i]);
  else          dst[i] = ((const float*)src)[i];
}

// ---------- Kernel 0c: pack mask into bits (bit i = element i) ----------
__global__ __launch_bounds__(256) void mask_pack(
    const void* __restrict__ mask, const int* __restrict__ flags,
    unsigned long long* __restrict__ bits) {
  const size_t idx = (size_t)blockIdx.x * 256 + threadIdx.x;
  const int mtype = flags[1];
  bool pred;
  if (mtype == 0)      pred = ((const int*)mask)[idx] != 0;
  else if (mtype == 1) pred = ((const unsigned char*)mask)[idx] != 0;
  else                 pred = (((const unsigned short*)mask)[idx] & 0x7FFF) != 0;
  const unsigned long long b = __ballot(pred);
  if ((threadIdx.x & 63) == 0) bits[idx >> 6] = b;
}

// ---------- Kernel A: xe = x @ W_w^T + W_b (fp32 + transposed bf16 out) ----------
__global__ __launch_bounds__(256) void xe_gemm(
    const float* __restrict__ x,
    const float* __restrict__ Ww,
    const float* __restrict__ Wb,
    float* __restrict__ xe_f,
    unsigned short* __restrict__ xeT) {   // [512 col][4096 n] bf16
  __shared__ float As[64][33];
  __shared__ float Bs[64][33];
  const int tid = threadIdx.x;
  const int n0 = blockIdx.x * 64;
  const int j0 = blockIdx.y * 64;
  const int lr = tid >> 2;          // 0..63
  const int lc = (tid & 3) * 8;     // 0,8,16,24
  const int ty = tid >> 4;
  const int tx = tid & 15;
  float c[4][4];
  #pragma unroll
  for (int i = 0; i < 4; ++i)
    #pragma unroll
    for (int j = 0; j < 4; ++j) c[i][j] = 0.f;

  for (int f0 = 0; f0 < F_IN; f0 += 32) {
    const float* ap = x  + (size_t)(n0 + lr) * F_IN + f0 + lc;
    const float* bp = Ww + (size_t)(j0 + lr) * F_IN + f0 + lc;
    const float4 a0 = *(const float4*)ap;
    const float4 a1 = *(const float4*)(ap + 4);
    const float4 b0 = *(const float4*)bp;
    const float4 b1 = *(const float4*)(bp + 4);
    __syncthreads();
    As[lr][lc + 0] = a0.x; As[lr][lc + 1] = a0.y;
    As[lr][lc + 2] = a0.z; As[lr][lc + 3] = a0.w;
    As[lr][lc + 4] = a1.x; As[lr][lc + 5] = a1.y;
    As[lr][lc + 6] = a1.z; As[lr][lc + 7] = a1.w;
    Bs[lr][lc + 0] = b0.x; Bs[lr][lc + 1] = b0.y;
    Bs[lr][lc + 2] = b0.z; Bs[lr][lc + 3] = b0.w;
    Bs[lr][lc + 4] = b1.x; Bs[lr][lc + 5] = b1.y;
    Bs[lr][lc + 6] = b1.z; Bs[lr][lc + 7] = b1.w;
    __syncthreads();
    #pragma unroll
    for (int kk = 0; kk < 32; ++kk) {
      float av[4], bv[4];
      #pragma unroll
      for (int i = 0; i < 4; ++i) av[i] = As[ty * 4 + i][kk];
      #pragma unroll
      for (int j = 0; j < 4; ++j) bv[j] = Bs[tx * 4 + j][kk];
      #pragma unroll
      for (int i = 0; i < 4; ++i)
        #pragma unroll
        for (int j = 0; j < 4; ++j) c[i][j] = fmaf(av[i], bv[j], c[i][j]);
    }
  }
  #pragma unroll
  for (int i = 0; i < 4; ++i) {
    const int n = n0 + ty * 4 + i;
    #pragma unroll
    for (int j = 0; j < 4; ++j) {
      const int col = j0 + tx * 4 + j;
      const float v = c[i][j] + Wb[col];
      xe_f[(size_t)n * KF + col] = v;
      xeT[(size_t)col * N_NODES + n] = f2bf(v);   // L2-merged scatter (4 MB total)
    }
  }
}

// ---------- Kernel B: hl[k,n], hr[k,n] ----------
__global__ __launch_bounds__(512) void hlr_kernel(
    const float* __restrict__ xe_f,
    const float* __restrict__ al,
    const float* __restrict__ ar,
    float* __restrict__ hl, float* __restrict__ hr) {
  const int n = blockIdx.x;
  const int t = threadIdx.x;        // t = k*64 + f
  const int k = t >> 6;
  const int f = t & 63;
  const float v = xe_f[(size_t)n * KF + t];
  float sl = v * al[t];
  float sr = v * ar[t];
  #pragma unroll
  for (int o = 32; o > 0; o >>= 1) {
    sl += __shfl_down(sl, o);
    sr += __shfl_down(sr, o);
  }
  if (f == 0) {
    hl[k * N_NODES + n] = sl;
    hr[k * N_NODES + n] = sr;
  }
}

// ---------- Kernel B2: per-head global max of hr ----------
__global__ __launch_bounds__(256) void hrmax_kernel(
    const float* __restrict__ hr, float* __restrict__ hrmax) {
  __shared__ float red[256];
  const int k = blockIdx.x;
  const int t = threadIdx.x;
  float m = -1e30f;
  for (int i = t; i < N_NODES; i += 256) m = fmaxf(m, hr[k * N_NODES + i]);
  red[t] = m;
  __syncthreads();
  for (int s = 128; s > 0; s >>= 1) {
    if (t < s) red[t] = fmaxf(red[t], red[t + s]);
    __syncthreads();
  }
  if (t == 0) hrmax[k] = red[0];
}

// ---------- Kernel C: mask passthrough -> fp32 {0,1}. Runs LAST. ----------
__global__ __launch_bounds__(256) void mask_copy(
    const void* __restrict__ mask, const int* __restrict__ flags,
    float* __restrict__ outm) {
  const size_t i4 = (size_t)blockIdx.x * 256 + threadIdx.x;  // 4 elems/thread
  const int mtype = flags[1];
  float4 o;
  if (mtype == 0) {
    const int4 mv = ((const int4*)mask)[i4];
    o.x = mv.x ? 1.f : 0.f; o.y = mv.y ? 1.f : 0.f;
    o.z = mv.z ? 1.f : 0.f; o.w = mv.w ? 1.f : 0.f;
  } else if (mtype == 1) {
    const unsigned mv = ((const unsigned*)mask)[i4];
    o.x = (mv & 0xFFu)         ? 1.f : 0.f;
    o.y = ((mv >> 8) & 0xFFu)  ? 1.f : 0.f;
    o.z = ((mv >> 16) & 0xFFu) ? 1.f : 0.f;
    o.w = (mv >> 24)           ? 1.f : 0.f;
  } else {
    const ushort4 mv = ((const ushort4*)mask)[i4];
    o.x = (mv.x & 0x7FFF) ? 1.f : 0.f; o.y = (mv.y & 0x7FFF) ? 1.f : 0.f;
    o.z = (mv.z & 0x7FFF) ? 1.f : 0.f; o.w = (mv.w & 0x7FFF) ? 1.f : 0.f;
  }
  ((float4*)outm)[i4] = o;
}

// ---------- Kernel D: fused attention, MFMA PV, barrier-free ----------
// One block = 16 rows; one wave = one head (8 waves). Per 64-m chunk:
//   stage 1 (VALU): lane=m computes w[r][m] (fp32 exp, bf16 round) -> private
//     LDS tile w_s[k] (same-wave write->read, lgkmcnt only, NO barriers).
//   stage 2 (MFMA): A = w (16x64 bf16, 2 frags), B = xeT (64x64 bf16 per head,
//     global L2), D += A*B via 8 x mfma_f32_16x16x32_bf16.
__global__ __launch_bounds__(512) void gat_attn(
    const unsigned long long* __restrict__ mbits,
    const float* __restrict__ hl,
    const float* __restrict__ hr,
    const float* __restrict__ hrmax,
    const unsigned short* __restrict__ xeT,
    float* __restrict__ out) {
  // per-head private LDS tile: [16 rows][72 m-cols (64 + 8 pad -> 2-way banks)]
  __shared__ __align__(16) short w_s[KH][16][72];   // 18.4 KB
  const int t = threadIdx.x;
  const int k = t >> 6;                 // wave = head
  const int lane = t & 63;
  const int n0 = blockIdx.x * 16;
  const int col16 = lane & 15;
  const int quad = lane >> 4;

  // per-row constants (wave-uniform, kept in VGPRs)
  const float hrmaxk = hrmax[k];
  float hlv[16], Mv[16];
  #pragma unroll
  for (int r = 0; r < 16; ++r) {
    hlv[r] = hl[k * N_NODES + n0 + r];
    const float s = hlv[r] + hrmaxk;
    Mv[r] = fmaxf(s, NEG_SLOPE * s);    // lrelu bound >= every score in row
  }

  floatx4 acc[4];
  #pragma unroll
  for (int ft = 0; ft < 4; ++ft) acc[ft] = (floatx4){0.f, 0.f, 0.f, 0.f};
  float dp[16];
  #pragma unroll
  for (int r = 0; r < 16; ++r) dp[r] = 0.f;

  const float* hr_k = hr + k * N_NODES;
  const unsigned long long* mrow = mbits + ((size_t)n0 << 6);  // [16 rows][64 u64]
  const unsigned short* xeT_k = xeT + (size_t)(k * 64) * N_NODES;

  for (int base = 0; base < N_NODES; base += 64) {
    // ---- stage 1: w[r][lane] for this chunk ----
    const float hrv = hr_k[base + lane];
    const int cidx = base >> 6;
    #pragma unroll
    for (int r = 0; r < 16; ++r) {
      const unsigned long long mb = mrow[(r << 6) + cidx];   // uniform per r
      float s = hlv[r] + hrv;
      s = fmaxf(s, NEG_SLOPE * s);
      float w = __expf(s - Mv[r]);
      w = ((mb >> lane) & 1ull) ? w : 0.f;
      const unsigned short wb = f2bf(w);
      w_s[k][r][lane] = (short)wb;
      dp[r] += bf2f(wb);                // denom consistent with rounded w
    }
    // ---- stage 2: 8 MFMA (compiler inserts lgkmcnt before A-frag reads) ----
    const short8 a0 = *(const short8*)&w_s[k][col16][quad * 8];       // m 0..31
    const short8 a1 = *(const short8*)&w_s[k][col16][32 + quad * 8];  // m 32..63
    #pragma unroll
    for (int ft = 0; ft < 4; ++ft) {
      const unsigned short* bcol =
          xeT_k + (size_t)(ft * 16 + col16) * N_NODES + base + quad * 8;
      const short8 b0 = *(const short8*)bcol;
      const short8 b1 = *(const short8*)(bcol + 32);
      acc[ft] = __builtin_amdgcn_mfma_f32_16x16x32_bf16(a0, b0, acc[ft], 0, 0, 0);
      acc[ft] = __builtin_amdgcn_mfma_f32_16x16x32_bf16(a1, b1, acc[ft], 0, 0, 0);
    }
  }

  // ---- reduce denominators across the wave (butterfly -> all lanes) ----
  #pragma unroll
  for (int r = 0; r < 16; ++r) {
    float v = dp[r];
    #pragma unroll
    for (int o = 32; o > 0; o >>= 1) v += __shfl_xor(v, o);
    dp[r] = v;
  }

  // ---- epilogue: normalize, elu(elu(.)), store fp32 ----
  // C/D layout (m89): col = lane&15, row = quad*4 + reg
  #pragma unroll
  for (int ft = 0; ft < 4; ++ft) {
    #pragma unroll
    for (int i = 0; i < 4; ++i) {
      const int row = quad * 4 + i;
      float v = acc[ft][i] / dp[row];
      v = (v > 0.f) ? v : (__expf(v) - 1.f);
      v = (v > 0.f) ? v : (__expf(v) - 1.f);
      out[(size_t)(n0 + row) * KF + k * 64 + ft * 16 + col16] = v;
    }
  }
}

// ---------- launcher ----------
extern "C" void kernel_launch(void* const* d_in, const int* in_sizes, int n_in,
                              void* d_out, int out_size, void* d_ws, size_t ws_size,
                              hipStream_t stream) {
  const void* x    = d_in[0];   // (4096,256)  fp32 (runtime-verified)
  const void* Ww   = d_in[1];   // (512,256)
  const void* Wb   = d_in[2];   // (512,)
  const void* al   = d_in[3];   // (1,8,64)
  const void* ar   = d_in[4];   // (1,8,64)
  const void* mask = d_in[5];   // (1,4096,4096) int32/bytes/16-bit (detected)

  float* out      = (float*)d_out;                    // (4096,512) fp32, 8 MB
  float* out_mask = out + (size_t)N_NODES * KF;       // (1,4096,4096) fp32, 64 MB

  // ---- scratch inside the 64 MB mask-passthrough region of d_out ----
  // mask_copy runs LAST and overwrites it with the real mask output.
  char* scratch = (char*)out_mask;
  float*          xe_f = (float*)scratch;                           // 8 MB @ 0
  unsigned short* xeT  = (unsigned short*)(scratch + (8u << 20));   // 4 MB @ 8M
  float*          hl   = (float*)(scratch + (12u << 20));           // 128 KB
  float*          hr   = hl + KH * N_NODES;                         // 128 KB
  float*          hrmx = hr + KH * N_NODES;                         // 32 B
  float*          x_f  = (float*)(scratch + (13u << 20));           // 4 MB
  float*          Ww_f = (float*)(scratch + (17u << 20));           // 512 KB
  float*          Wb_f = (float*)(scratch + (17u << 20) + (640u << 10)); // 2 KB
  float*          al_f = Wb_f + 512;
  float*          ar_f = al_f + 512;
  int*            flags= (int*)(ar_f + 512);
  unsigned long long* mbits = (unsigned long long*)(scratch + (18u << 20)); // 2 MB
  // top of use: 20 MB < 64 MB available

  // 0: detect dtypes
  detect_kernel<<<1, 64, 0, stream>>>((const unsigned*)x, (const unsigned*)mask, flags);

  // 0b: canonicalize float inputs to fp32
  convert_in<<<4096, 256, 0, stream>>>(x,  x_f,  N_NODES * F_IN, flags);
  convert_in<<<512, 256, 0, stream>>>(Ww, Ww_f, KF * F_IN, flags);
  convert_in<<<2, 256, 0, stream>>>(Wb, Wb_f, KF, flags);
  convert_in<<<2, 256, 0, stream>>>(al, al_f, KF, flags);
  convert_in<<<2, 256, 0, stream>>>(ar, ar_f, KF, flags);

  // 0c: bit-pack the mask
  mask_pack<<<(N_NODES * (size_t)N_NODES) / 256, 256, 0, stream>>>(mask, flags, mbits);

  // A: xe = x @ W^T + b  (+ transposed bf16 copy for MFMA B-operand)
  dim3 ga(N_NODES / 64, KF / 64);
  xe_gemm<<<ga, 256, 0, stream>>>(x_f, Ww_f, Wb_f, xe_f, xeT);

  // B: hl, hr
  hlr_kernel<<<N_NODES, 512, 0, stream>>>(xe_f, al_f, ar_f, hl, hr);

  // B2: per-head hr max (softmax shift bound)
  hrmax_kernel<<<KH, 256, 0, stream>>>(hr, hrmx);

  // D: fused attention (consumes all scratch)
  gat_attn<<<N_NODES / 16, 512, 0, stream>>>(mbits, hl, hr, hrmx, xeT, out);

  // C: mask passthrough — LAST, overwrites the scratch region with real output
  mask_copy<<<(N_NODES * (size_t)N_NODES) / (4 * 256), 256, 0, stream>>>(mask, flags, out_mask);
}

// Round 6
// 342.258 us; speedup vs baseline: 2.8904x; 1.2231x over previous
//
#include <hip/hip_runtime.h>
#include <hip/hip_bf16.h>

// Problem constants (GAT_18176301597437)
#define N_NODES 4096
#define F_IN    256
#define KH      8
#define KF      512          // KH*FPH
#define NEG_SLOPE 0.2f

typedef __attribute__((ext_vector_type(8))) short short8;   // 8 bf16 = 4 VGPRs
typedef __attribute__((ext_vector_type(4))) float floatx4;  // MFMA C/D

union S8U4 { short8 v; unsigned u[4]; };

__device__ __forceinline__ unsigned short f2bf(float f) {
    __hip_bfloat16 h = __float2bfloat16(f);
    unsigned short u; __builtin_memcpy(&u, &h, 2);
    return u;
}

// ---------- mask_pack: int32 {0,1} -> bit per element ----------
__global__ __launch_bounds__(256) void mask_pack(
    const int* __restrict__ mask, unsigned long long* __restrict__ bits) {
  const size_t idx = (size_t)blockIdx.x * 256 + threadIdx.x;
  const unsigned long long b = __ballot(mask[idx] != 0);
  if ((threadIdx.x & 63) == 0) bits[idx >> 6] = b;
}

// ---------- mask_copy: int32 -> fp32 {0,1} passthrough. Runs LAST. ----------
__global__ __launch_bounds__(256) void mask_copy(
    const int* __restrict__ mask, float* __restrict__ outm) {
  const size_t i4 = (size_t)blockIdx.x * 256 + threadIdx.x;
  const int4 mv = ((const int4*)mask)[i4];
  float4 o;
  o.x = mv.x ? 1.f : 0.f; o.y = mv.y ? 1.f : 0.f;
  o.z = mv.z ? 1.f : 0.f; o.w = mv.w ? 1.f : 0.f;
  ((float4*)outm)[i4] = o;
}

// ---------- Kernel A: xe = x @ W_w^T + W_b (fp32 + transposed bf16 out) ----------
// LDS transposed to [kk][row] so the inner loop reads 2 x ds_read_b128 per kk.
__global__ __launch_bounds__(256) void xe_gemm(
    const float* __restrict__ x,
    const float* __restrict__ Ww,
    const float* __restrict__ Wb,
    float* __restrict__ xe_f,
    unsigned short* __restrict__ xeT) {   // [512 col][4096 n] bf16
  __shared__ float As[32][65];
  __shared__ float Bs[32][65];
  const int tid = threadIdx.x;
  const int n0 = blockIdx.x * 64;
  const int j0 = blockIdx.y * 64;
  const int lr = tid >> 2;          // 0..63 row
  const int lc = (tid & 3) * 8;     // 0,8,16,24 k-offset
  const int ty = tid >> 4;
  const int tx = tid & 15;
  float c[4][4];
  #pragma unroll
  for (int i = 0; i < 4; ++i)
    #pragma unroll
    for (int j = 0; j < 4; ++j) c[i][j] = 0.f;

  for (int f0 = 0; f0 < F_IN; f0 += 32) {
    const float* ap = x  + (size_t)(n0 + lr) * F_IN + f0 + lc;
    const float* bp = Ww + (size_t)(j0 + lr) * F_IN + f0 + lc;
    const float4 a0 = *(const float4*)ap;
    const float4 a1 = *(const float4*)(ap + 4);
    const float4 b0 = *(const float4*)bp;
    const float4 b1 = *(const float4*)(bp + 4);
    __syncthreads();
    As[lc + 0][lr] = a0.x; As[lc + 1][lr] = a0.y;
    As[lc + 2][lr] = a0.z; As[lc + 3][lr] = a0.w;
    As[lc + 4][lr] = a1.x; As[lc + 5][lr] = a1.y;
    As[lc + 6][lr] = a1.z; As[lc + 7][lr] = a1.w;
    Bs[lc + 0][lr] = b0.x; Bs[lc + 1][lr] = b0.y;
    Bs[lc + 2][lr] = b0.z; Bs[lc + 3][lr] = b0.w;
    Bs[lc + 4][lr] = b1.x; Bs[lc + 5][lr] = b1.y;
    Bs[lc + 6][lr] = b1.z; Bs[lc + 7][lr] = b1.w;
    __syncthreads();
    #pragma unroll
    for (int kk = 0; kk < 32; ++kk) {
      const float4 av = *(const float4*)&As[kk][ty * 4];
      const float4 bv = *(const float4*)&Bs[kk][tx * 4];
      const float a4[4] = {av.x, av.y, av.z, av.w};
      const float b4[4] = {bv.x, bv.y, bv.z, bv.w};
      #pragma unroll
      for (int i = 0; i < 4; ++i)
        #pragma unroll
        for (int j = 0; j < 4; ++j) c[i][j] = fmaf(a4[i], b4[j], c[i][j]);
    }
  }
  #pragma unroll
  for (int i = 0; i < 4; ++i) {
    const int n = n0 + ty * 4 + i;
    #pragma unroll
    for (int j = 0; j < 4; ++j) {
      const int col = j0 + tx * 4 + j;
      const float v = c[i][j] + Wb[col];
      xe_f[(size_t)n * KF + col] = v;
      xeT[(size_t)col * N_NODES + n] = f2bf(v);
    }
  }
}

// ---------- Kernel B: hl[k,n], hr[k,n] ----------
__global__ __launch_bounds__(512) void hlr_kernel(
    const float* __restrict__ xe_f,
    const float* __restrict__ al,
    const float* __restrict__ ar,
    float* __restrict__ hl, float* __restrict__ hr) {
  const int n = blockIdx.x;
  const int t = threadIdx.x;        // t = k*64 + f
  const int k = t >> 6;
  const int f = t & 63;
  const float v = xe_f[(size_t)n * KF + t];
  float sl = v * al[t];
  float sr = v * ar[t];
  #pragma unroll
  for (int o = 32; o > 0; o >>= 1) {
    sl += __shfl_down(sl, o);
    sr += __shfl_down(sr, o);
  }
  if (f == 0) {
    hl[k * N_NODES + n] = sl;
    hr[k * N_NODES + n] = sr;
  }
}

// ---------- Kernel B2: per-head global max of hr ----------
__global__ __launch_bounds__(256) void hrmax_kernel(
    const float* __restrict__ hr, float* __restrict__ hrmax) {
  __shared__ float red[256];
  const int k = blockIdx.x;
  const int t = threadIdx.x;
  float m = -1e30f;
  for (int i = t; i < N_NODES; i += 256) m = fmaxf(m, hr[k * N_NODES + i]);
  red[t] = m;
  __syncthreads();
  for (int s = 128; s > 0; s >>= 1) {
    if (t < s) red[t] = fmaxf(red[t], red[t + s]);
    __syncthreads();
  }
  if (t == 0) hrmax[k] = red[0];
}

// ---------- Kernel D: fused attention, register-resident A-fragments ----------
// Block = 256 thr = 4 waves = one (16-row group, head); wave = m-quarter.
// Each lane computes w DIRECTLY in MFMA A-layout (row = lane&15,
// m = quad*8 + j) — no LDS transpose, no barriers in the main loop.
// Partial acc/dp combined across the 4 waves via LDS at the end.
__global__ __launch_bounds__(256) void gat_attn(
    const unsigned long long* __restrict__ mbits,
    const float* __restrict__ hl,
    const float* __restrict__ hr,
    const float* __restrict__ hrmax,
    const unsigned short* __restrict__ xeT,
    float* __restrict__ out) {
  __shared__ float lds_acc[3][64][17];   // 12.75 KB
  __shared__ float lds_dp[3][16];
  const int t = threadIdx.x;
  const int wq = t >> 6;                // m-quarter 0..3
  const int lane = t & 63;
  const int rg = blockIdx.x >> 3;       // row-group 0..255
  const int k  = blockIdx.x & 7;        // head
  const int n0 = rg * 16;
  const int row = lane & 15;
  const int quad = lane >> 4;
  const int q8 = quad * 8;

  const float hlv = hl[k * N_NODES + n0 + row];
  const float sM = hlv + hrmax[k];
  const float Mv = fmaxf(sM, NEG_SLOPE * sM);   // >= every score in this row

  const float* hr_k = hr + k * N_NODES;
  const unsigned short* xeT_k = xeT + (size_t)(k * 64) * N_NODES;
  const unsigned long long* mrow = mbits + ((size_t)(n0 + row) << 6);

  floatx4 acc[4];
  #pragma unroll
  for (int ft = 0; ft < 4; ++ft) acc[ft] = (floatx4){0.f, 0.f, 0.f, 0.f};
  float dp = 0.f;

  const int c1 = wq * 16 + 16;
  for (int c = wq * 16; c < c1; ++c) {
    const int base = c * 64;
    const unsigned long long mb = mrow[c];
    const unsigned mlo = (unsigned)(mb >> q8);          // bits for m = base+q8+j
    const unsigned mhi = (unsigned)(mb >> (32 + q8));   // m = base+32+q8+j

    S8U4 a0, a1;
    {
      const float4 h0 = *(const float4*)(hr_k + base + q8);
      const float4 h1 = *(const float4*)(hr_k + base + q8 + 4);
      const float hrs[8] = {h0.x, h0.y, h0.z, h0.w, h1.x, h1.y, h1.z, h1.w};
      float w[8];
      #pragma unroll
      for (int j = 0; j < 8; ++j) {
        float s = hlv + hrs[j];
        s = fmaxf(s, NEG_SLOPE * s);
        float e = __expf(s - Mv);
        e = ((mlo >> j) & 1u) ? e : 0.f;
        w[j] = e; dp += e;
      }
      #pragma unroll
      for (int p = 0; p < 4; ++p) {
        unsigned u0, u1;
        __builtin_memcpy(&u0, &w[2 * p], 4);
        __builtin_memcpy(&u1, &w[2 * p + 1], 4);
        a0.u[p] = ((u0 + 0x8000u) >> 16) | ((u1 + 0x8000u) & 0xFFFF0000u);
      }
    }
    {
      const float4 h2 = *(const float4*)(hr_k + base + 32 + q8);
      const float4 h3 = *(const float4*)(hr_k + base + 32 + q8 + 4);
      const float hrs[8] = {h2.x, h2.y, h2.z, h2.w, h3.x, h3.y, h3.z, h3.w};
      float w[8];
      #pragma unroll
      for (int j = 0; j < 8; ++j) {
        float s = hlv + hrs[j];
        s = fmaxf(s, NEG_SLOPE * s);
        float e = __expf(s - Mv);
        e = ((mhi >> j) & 1u) ? e : 0.f;
        w[j] = e; dp += e;
      }
      #pragma unroll
      for (int p = 0; p < 4; ++p) {
        unsigned u0, u1;
        __builtin_memcpy(&u0, &w[2 * p], 4);
        __builtin_memcpy(&u1, &w[2 * p + 1], 4);
        a1.u[p] = ((u0 + 0x8000u) >> 16) | ((u1 + 0x8000u) & 0xFFFF0000u);
      }
    }
    #pragma unroll
    for (int ft = 0; ft < 4; ++ft) {
      const unsigned short* bcol =
          xeT_k + (size_t)(ft * 16 + row) * N_NODES + base + q8;
      const short8 b0 = *(const short8*)bcol;
      const short8 b1 = *(const short8*)(bcol + 32);
      acc[ft] = __builtin_amdgcn_mfma_f32_16x16x32_bf16(a0.v, b0, acc[ft], 0, 0, 0);
      acc[ft] = __builtin_amdgcn_mfma_f32_16x16x32_bf16(a1.v, b1, acc[ft], 0, 0, 0);
    }
  }

  // intra-wave dp reduce over the 4 m-subquads (lane bits 4,5)
  dp += __shfl_xor(dp, 16);
  dp += __shfl_xor(dp, 32);

  // cross-wave combine (waves 1..3 -> wave 0)
  if (wq > 0) {
    #pragma unroll
    for (int i = 0; i < 16; ++i) lds_acc[wq - 1][lane][i] = acc[i >> 2][i & 3];
    if (lane < 16) lds_dp[wq - 1][lane] = dp;
  }
  __syncthreads();
  if (wq == 0) {
    #pragma unroll
    for (int w2 = 0; w2 < 3; ++w2) {
      #pragma unroll
      for (int i = 0; i < 16; ++i) acc[i >> 2][i & 3] += lds_acc[w2][lane][i];
      dp += lds_dp[w2][row];
    }
    float dr[4];
    #pragma unroll
    for (int i = 0; i < 4; ++i) dr[i] = __shfl(dp, quad * 4 + i);
    #pragma unroll
    for (int ft = 0; ft < 4; ++ft) {
      #pragma unroll
      for (int i = 0; i < 4; ++i) {
        const int r2 = quad * 4 + i;
        float v = acc[ft][i] / dr[i];
        v = (v > 0.f) ? v : (__expf(v) - 1.f);
        v = (v > 0.f) ? v : (__expf(v) - 1.f);
        out[(size_t)(n0 + r2) * KF + k * 64 + ft * 16 + row] = v;
      }
    }
  }
}

// ---------- launcher ----------
extern "C" void kernel_launch(void* const* d_in, const int* in_sizes, int n_in,
                              void* d_out, int out_size, void* d_ws, size_t ws_size,
                              hipStream_t stream) {
  const float* x    = (const float*)d_in[0];   // (4096,256) fp32
  const float* Ww   = (const float*)d_in[1];   // (512,256)  fp32
  const float* Wb   = (const float*)d_in[2];   // (512,)     fp32
  const float* al   = (const float*)d_in[3];   // (1,8,64)   fp32
  const float* ar   = (const float*)d_in[4];   // (1,8,64)   fp32
  const int*   mask = (const int*)d_in[5];     // (1,4096,4096) int32

  float* out      = (float*)d_out;                    // (4096,512) fp32, 8 MB
  float* out_mask = out + (size_t)N_NODES * KF;       // (1,4096,4096) fp32, 64 MB

  // scratch inside the 64 MB mask-passthrough region; mask_copy runs LAST
  char* scratch = (char*)out_mask;
  float*          xe_f = (float*)scratch;                           // 8 MB
  unsigned short* xeT  = (unsigned short*)(scratch + (8u << 20));   // 4 MB
  float*          hl   = (float*)(scratch + (12u << 20));           // 128 KB
  float*          hr   = hl + KH * N_NODES;                         // 128 KB
  float*          hrmx = hr + KH * N_NODES;                         // 32 B
  unsigned long long* mbits = (unsigned long long*)(scratch + (13u << 20)); // 2 MB
  // top of use: 15 MB < 64 MB

  // A: xe = x @ W^T + b (+ transposed bf16 copy)
  dim3 ga(N_NODES / 64, KF / 64);
  xe_gemm<<<ga, 256, 0, stream>>>(x, Ww, Wb, xe_f, xeT);

  // B: hl, hr;  B2: per-head hr max
  hlr_kernel<<<N_NODES, 512, 0, stream>>>(xe_f, al, ar, hl, hr);
  hrmax_kernel<<<KH, 256, 0, stream>>>(hr, hrmx);

  // bit-pack the mask
  mask_pack<<<(N_NODES * (size_t)N_NODES) / 256, 256, 0, stream>>>(mask, mbits);

  // D: fused attention (2048 blocks = 256 row-groups x 8 heads)
  gat_attn<<<256 * KH, 256, 0, stream>>>(mbits, hl, hr, hrmx, xeT, out);

  // mask passthrough — LAST, overwrites scratch
  mask_copy<<<(N_NODES * (size_t)N_NODES) / (4 * 256), 256, 0, stream>>>(mask, out_mask);
}

// Round 7
// 307.762 us; speedup vs baseline: 3.2144x; 1.1121x over previous
//
#include <hip/hip_runtime.h>
#include <hip/hip_bf16.h>

// Problem constants (GAT_18176301597437)
#define N_NODES 4096
#define F_IN    256
#define KH      8
#define KF      512          // KH*FPH
#define NEG_SLOPE 0.2f

typedef __attribute__((ext_vector_type(8))) short short8;   // 8 bf16 = 4 VGPRs
typedef __attribute__((ext_vector_type(4))) float floatx4;  // MFMA C/D

union S8U4 { short8 v; unsigned u[4]; };

__device__ __forceinline__ unsigned short f2bf(float f) {
    __hip_bfloat16 h = __float2bfloat16(f);
    unsigned short u; __builtin_memcpy(&u, &h, 2);
    return u;
}

// ---------- mask_fused: one pass -> fp32 passthrough + bit-pack ----------
// Block = 256 thr = 4 waves, 1024 elems. Thread handles e = base + c*256 + tid,
// so each wave's 64 lanes cover one contiguous u64 bit-word per c.
__global__ __launch_bounds__(256) void mask_fused(
    const int* __restrict__ mask, float* __restrict__ outm,
    unsigned long long* __restrict__ bits) {
  const size_t base = (size_t)blockIdx.x * 1024;
  const int tid = threadIdx.x;
  #pragma unroll
  for (int c = 0; c < 4; ++c) {
    const size_t e = base + c * 256 + tid;
    const int v = mask[e];
    outm[e] = v ? 1.f : 0.f;
    const unsigned long long b = __ballot(v != 0);
    if ((tid & 63) == 0) bits[e >> 6] = b;
  }
}

// ---------- fallback pair (scratch inside out_mask region) ----------
__global__ __launch_bounds__(256) void mask_pack(
    const int* __restrict__ mask, unsigned long long* __restrict__ bits) {
  const size_t idx = (size_t)blockIdx.x * 256 + threadIdx.x;
  const unsigned long long b = __ballot(mask[idx] != 0);
  if ((threadIdx.x & 63) == 0) bits[idx >> 6] = b;
}
__global__ __launch_bounds__(256) void mask_copy(
    const int* __restrict__ mask, float* __restrict__ outm) {
  const size_t i4 = (size_t)blockIdx.x * 256 + threadIdx.x;
  const int4 mv = ((const int4*)mask)[i4];
  float4 o;
  o.x = mv.x ? 1.f : 0.f; o.y = mv.y ? 1.f : 0.f;
  o.z = mv.z ? 1.f : 0.f; o.w = mv.w ? 1.f : 0.f;
  ((float4*)outm)[i4] = o;
}

// ---------- Kernel A: xe-GEMM + fused hl/hr epilogue ----------
// Tile 64x64; by = head (64 cols = 1 head). Epilogue: per-thread 4x4 dot with
// a_left/a_right + 16-lane shfl reduce -> hl/hr written directly (fp32 path;
// xe_f never materialized). xeT bf16 transposed for the MFMA B-operand.
__global__ __launch_bounds__(256) void xe_gemm(
    const float* __restrict__ x,
    const float* __restrict__ Ww,
    const float* __restrict__ Wb,
    const float* __restrict__ al,
    const float* __restrict__ ar,
    unsigned short* __restrict__ xeT,   // [512 col][4096 n] bf16
    float* __restrict__ hl,             // [8][4096]
    float* __restrict__ hr) {
  __shared__ float As[32][65];
  __shared__ float Bs[32][65];
  const int tid = threadIdx.x;
  const int n0 = blockIdx.x * 64;
  const int j0 = blockIdx.y * 64;
  const int lr = tid >> 2;          // 0..63 row
  const int lc = (tid & 3) * 8;     // 0,8,16,24 k-offset
  const int ty = tid >> 4;
  const int tx = tid & 15;
  float c[4][4];
  #pragma unroll
  for (int i = 0; i < 4; ++i)
    #pragma unroll
    for (int j = 0; j < 4; ++j) c[i][j] = 0.f;

  for (int f0 = 0; f0 < F_IN; f0 += 32) {
    const float* ap = x  + (size_t)(n0 + lr) * F_IN + f0 + lc;
    const float* bp = Ww + (size_t)(j0 + lr) * F_IN + f0 + lc;
    const float4 a0 = *(const float4*)ap;
    const float4 a1 = *(const float4*)(ap + 4);
    const float4 b0 = *(const float4*)bp;
    const float4 b1 = *(const float4*)(bp + 4);
    __syncthreads();
    As[lc + 0][lr] = a0.x; As[lc + 1][lr] = a0.y;
    As[lc + 2][lr] = a0.z; As[lc + 3][lr] = a0.w;
    As[lc + 4][lr] = a1.x; As[lc + 5][lr] = a1.y;
    As[lc + 6][lr] = a1.z; As[lc + 7][lr] = a1.w;
    Bs[lc + 0][lr] = b0.x; Bs[lc + 1][lr] = b0.y;
    Bs[lc + 2][lr] = b0.z; Bs[lc + 3][lr] = b0.w;
    Bs[lc + 4][lr] = b1.x; Bs[lc + 5][lr] = b1.y;
    Bs[lc + 6][lr] = b1.z; Bs[lc + 7][lr] = b1.w;
    __syncthreads();
    #pragma unroll
    for (int kk = 0; kk < 32; ++kk) {
      const float4 av = *(const float4*)&As[kk][ty * 4];
      const float4 bv = *(const float4*)&Bs[kk][tx * 4];
      const float a4[4] = {av.x, av.y, av.z, av.w};
      const float b4[4] = {bv.x, bv.y, bv.z, bv.w};
      #pragma unroll
      for (int i = 0; i < 4; ++i)
        #pragma unroll
        for (int j = 0; j < 4; ++j) c[i][j] = fmaf(a4[i], b4[j], c[i][j]);
    }
  }
  // bias + stores + hl/hr partials
  const float4 wb4 = *(const float4*)(Wb + j0 + tx * 4);
  const float4 al4 = *(const float4*)(al + j0 + tx * 4);
  const float4 ar4 = *(const float4*)(ar + j0 + tx * 4);
  const float wb[4] = {wb4.x, wb4.y, wb4.z, wb4.w};
  const float alv[4] = {al4.x, al4.y, al4.z, al4.w};
  const float arv[4] = {ar4.x, ar4.y, ar4.z, ar4.w};
  float pl[4], pr[4];
  #pragma unroll
  for (int i = 0; i < 4; ++i) {
    const int n = n0 + ty * 4 + i;
    float sl = 0.f, sr = 0.f;
    #pragma unroll
    for (int j = 0; j < 4; ++j) {
      const float v = c[i][j] + wb[j];
      xeT[(size_t)(j0 + tx * 4 + j) * N_NODES + n] = f2bf(v);
      sl = fmaf(v, alv[j], sl);
      sr = fmaf(v, arv[j], sr);
    }
    pl[i] = sl; pr[i] = sr;
  }
  // reduce over the 16 tx lanes (contiguous within a wave)
  #pragma unroll
  for (int off = 8; off > 0; off >>= 1) {
    #pragma unroll
    for (int i = 0; i < 4; ++i) {
      pl[i] += __shfl_down(pl[i], off);
      pr[i] += __shfl_down(pr[i], off);
    }
  }
  if (tx == 0) {
    const int k = j0 >> 6;
    float4 o0 = {pl[0], pl[1], pl[2], pl[3]};
    float4 o1 = {pr[0], pr[1], pr[2], pr[3]};
    *(float4*)(hl + k * N_NODES + n0 + ty * 4) = o0;
    *(float4*)(hr + k * N_NODES + n0 + ty * 4) = o1;
  }
}

// ---------- Kernel B2: per-head global max of hr ----------
__global__ __launch_bounds__(256) void hrmax_kernel(
    const float* __restrict__ hr, float* __restrict__ hrmax) {
  __shared__ float red[256];
  const int k = blockIdx.x;
  const int t = threadIdx.x;
  float m = -1e30f;
  for (int i = t; i < N_NODES; i += 256) m = fmaxf(m, hr[k * N_NODES + i]);
  red[t] = m;
  __syncthreads();
  for (int s = 128; s > 0; s >>= 1) {
    if (t < s) red[t] = fmaxf(red[t], red[t + s]);
    __syncthreads();
  }
  if (t == 0) hrmax[k] = red[0];
}

// ---------- Kernel D: fused attention ----------
// Block = 512 thr = 8 waves = one (16-row group, head); wave = 8 m-chunks.
// w computed directly in MFMA A-layout in registers; partials combined via
// LDS once; epilogue spread across all 8 waves.
__global__ __launch_bounds__(512) void gat_attn(
    const unsigned long long* __restrict__ mbits,
    const float* __restrict__ hl,
    const float* __restrict__ hr,
    const float* __restrict__ hrmax,
    const unsigned short* __restrict__ xeT,
    float* __restrict__ out) {
  __shared__ float lds_acc[8][64][18];   // 36.9 KB (stride 18: b64-friendly)
  __shared__ float lds_dp[8][16];
  const int t = threadIdx.x;
  const int w8 = t >> 6;                // wave 0..7 = m-eighth
  const int lane = t & 63;
  const int rg = blockIdx.x >> 3;       // row-group 0..255
  const int k  = blockIdx.x & 7;        // head
  const int n0 = rg * 16;
  const int row = lane & 15;
  const int quad = lane >> 4;
  const int q8 = quad * 8;

  const float hlv = hl[k * N_NODES + n0 + row];
  const float sM = hlv + hrmax[k];
  const float Mv = fmaxf(sM, NEG_SLOPE * sM);   // >= every score in this row

  const float* hr_k = hr + k * N_NODES;
  const unsigned short* xeT_k = xeT + (size_t)(k * 64) * N_NODES;
  const unsigned long long* mrow = mbits + ((size_t)(n0 + row) << 6);

  floatx4 acc[4];
  #pragma unroll
  for (int ft = 0; ft < 4; ++ft) acc[ft] = (floatx4){0.f, 0.f, 0.f, 0.f};
  float dp = 0.f;

  const int c0 = w8 * 8;
  #pragma unroll 2
  for (int c = c0; c < c0 + 8; ++c) {
    const int base = c * 64;
    const unsigned long long mb = mrow[c];
    const unsigned mlo = (unsigned)(mb >> q8);
    const unsigned mhi = (unsigned)(mb >> (32 + q8));

    S8U4 a0, a1;
    {
      const float4 h0 = *(const float4*)(hr_k + base + q8);
      const float4 h1 = *(const float4*)(hr_k + base + q8 + 4);
      const float hrs[8] = {h0.x, h0.y, h0.z, h0.w, h1.x, h1.y, h1.z, h1.w};
      float w[8];
      #pragma unroll
      for (int j = 0; j < 8; ++j) {
        float s = hlv + hrs[j];
        s = fmaxf(s, NEG_SLOPE * s);
        float e = __expf(s - Mv);
        e = ((mlo >> j) & 1u) ? e : 0.f;
        w[j] = e; dp += e;
      }
      #pragma unroll
      for (int p = 0; p < 4; ++p) {
        unsigned u0, u1;
        __builtin_memcpy(&u0, &w[2 * p], 4);
        __builtin_memcpy(&u1, &w[2 * p + 1], 4);
        a0.u[p] = ((u0 + 0x8000u) >> 16) | ((u1 + 0x8000u) & 0xFFFF0000u);
      }
    }
    {
      const float4 h2 = *(const float4*)(hr_k + base + 32 + q8);
      const float4 h3 = *(const float4*)(hr_k + base + 32 + q8 + 4);
      const float hrs[8] = {h2.x, h2.y, h2.z, h2.w, h3.x, h3.y, h3.z, h3.w};
      float w[8];
      #pragma unroll
      for (int j = 0; j < 8; ++j) {
        float s = hlv + hrs[j];
        s = fmaxf(s, NEG_SLOPE * s);
        float e = __expf(s - Mv);
        e = ((mhi >> j) & 1u) ? e : 0.f;
        w[j] = e; dp += e;
      }
      #pragma unroll
      for (int p = 0; p < 4; ++p) {
        unsigned u0, u1;
        __builtin_memcpy(&u0, &w[2 * p], 4);
        __builtin_memcpy(&u1, &w[2 * p + 1], 4);
        a1.u[p] = ((u0 + 0x8000u) >> 16) | ((u1 + 0x8000u) & 0xFFFF0000u);
      }
    }
    #pragma unroll
    for (int ft = 0; ft < 4; ++ft) {
      const unsigned short* bcol =
          xeT_k + (size_t)(ft * 16 + row) * N_NODES + base + q8;
      const short8 b0 = *(const short8*)bcol;
      const short8 b1 = *(const short8*)(bcol + 32);
      acc[ft] = __builtin_amdgcn_mfma_f32_16x16x32_bf16(a0.v, b0, acc[ft], 0, 0, 0);
      acc[ft] = __builtin_amdgcn_mfma_f32_16x16x32_bf16(a1.v, b1, acc[ft], 0, 0, 0);
    }
  }

  // dp: reduce over the 4 quads -> every lane holds total for row=lane&15
  dp += __shfl_xor(dp, 16);
  dp += __shfl_xor(dp, 32);

  // write partials
  #pragma unroll
  for (int i = 0; i < 16; ++i) lds_acc[w8][lane][i] = acc[i >> 2][i & 3];
  if (lane < 16) lds_dp[w8][lane] = dp;
  __syncthreads();

  // wave w8 finalizes output slots i = {2*w8, 2*w8+1} (same ft = w8>>1)
  const int ftq = w8 >> 1;
  float fa[2] = {0.f, 0.f};
  #pragma unroll
  for (int w2 = 0; w2 < 8; ++w2) {
    fa[0] += lds_acc[w2][lane][2 * w8];
    fa[1] += lds_acc[w2][lane][2 * w8 + 1];
  }
  #pragma unroll
  for (int j = 0; j < 2; ++j) {
    const int reg = (2 * w8 + j) & 3;
    const int row_o = quad * 4 + reg;
    float dpt = 0.f;
    #pragma unroll
    for (int w2 = 0; w2 < 8; ++w2) dpt += lds_dp[w2][row_o];
    float v = fa[j] / dpt;
    v = (v > 0.f) ? v : (__expf(v) - 1.f);
    v = (v > 0.f) ? v : (__expf(v) - 1.f);
    out[(size_t)(n0 + row_o) * KF + k * 64 + ftq * 16 + row] = v;
  }
}

// ---------- launcher ----------
extern "C" void kernel_launch(void* const* d_in, const int* in_sizes, int n_in,
                              void* d_out, int out_size, void* d_ws, size_t ws_size,
                              hipStream_t stream) {
  const float* x    = (const float*)d_in[0];   // (4096,256) fp32
  const float* Ww   = (const float*)d_in[1];   // (512,256)  fp32
  const float* Wb   = (const float*)d_in[2];   // (512,)     fp32
  const float* al   = (const float*)d_in[3];   // (1,8,64)   fp32
  const float* ar   = (const float*)d_in[4];   // (1,8,64)   fp32
  const int*   mask = (const int*)d_in[5];     // (1,4096,4096) int32

  float* out      = (float*)d_out;                    // (4096,512) fp32, 8 MB
  float* out_mask = out + (size_t)N_NODES * KF;       // (1,4096,4096) fp32, 64 MB

  const bool use_ws = (ws_size >= (8u << 20));
  // scratch: d_ws when big enough (lets mask run fused, one pass);
  // else inside out_mask region with pack-early / copy-last ordering.
  char* scratch = use_ws ? (char*)d_ws : (char*)out_mask;
  unsigned short* xeT  = (unsigned short*)scratch;                 // 4 MB
  float*          hl   = (float*)(scratch + (4u << 20));           // 128 KB
  float*          hr   = hl + KH * N_NODES;                        // 128 KB
  float*          hrmx = hr + KH * N_NODES;                        // 32 B
  unsigned long long* mbits = (unsigned long long*)(scratch + (5u << 20)); // 2 MB
  // top of use: 7 MB

  // A: xe-GEMM + hl/hr fused epilogue (+ transposed bf16 xe)
  dim3 ga(N_NODES / 64, KF / 64);
  xe_gemm<<<ga, 256, 0, stream>>>(x, Ww, Wb, al, ar, xeT, hl, hr);

  // B2: per-head hr max
  hrmax_kernel<<<KH, 256, 0, stream>>>(hr, hrmx);

  if (use_ws) {
    // single-pass mask: passthrough + bits
    mask_fused<<<(N_NODES * (size_t)N_NODES) / 1024, 256, 0, stream>>>(
        mask, out_mask, mbits);
    gat_attn<<<256 * KH, 512, 0, stream>>>(mbits, hl, hr, hrmx, xeT, out);
  } else {
    mask_pack<<<(N_NODES * (size_t)N_NODES) / 256, 256, 0, stream>>>(mask, mbits);
    gat_attn<<<256 * KH, 512, 0, stream>>>(mbits, hl, hr, hrmx, xeT, out);
    mask_copy<<<(N_NODES * (size_t)N_NODES) / (4 * 256), 256, 0, stream>>>(mask, out_mask);
  }
}

// Round 8
// 267.807 us; speedup vs baseline: 3.6940x; 1.1492x over previous
//
#include <hip/hip_runtime.h>
#include <hip/hip_bf16.h>

// Problem constants (GAT_18176301597437)
#define N_NODES 4096
#define F_IN    256
#define KH      8
#define KF      512          // KH*FPH
#define NEG_SLOPE 0.2f

typedef __attribute__((ext_vector_type(8))) short short8;   // 8 bf16 = 4 VGPRs
typedef __attribute__((ext_vector_type(4))) float floatx4;  // MFMA C/D

union S8U4 { short8 v; unsigned u[4]; };

__device__ __forceinline__ unsigned short f2bf(float f) {
    __hip_bfloat16 h = __float2bfloat16(f);
    unsigned short u; __builtin_memcpy(&u, &h, 2);
    return u;
}

// ---------- mask_fused: one pass -> fp32 passthrough + TRANSPOSED bit-pack ----
// bits layout: word index = c*4096 + n   (c = m-chunk = (m>>6), n = row)
__global__ __launch_bounds__(256) void mask_fused(
    const int* __restrict__ mask, float* __restrict__ outm,
    unsigned long long* __restrict__ bits) {
  const size_t base = (size_t)blockIdx.x * 1024;
  const int tid = threadIdx.x;
  #pragma unroll
  for (int c = 0; c < 4; ++c) {
    const size_t e = base + c * 256 + tid;
    const int v = mask[e];
    outm[e] = v ? 1.f : 0.f;
    const unsigned long long b = __ballot(v != 0);
    if ((tid & 63) == 0) {
      const size_t w = e >> 6;                    // linear word index
      bits[(w & 63) * (size_t)N_NODES + (w >> 6)] = b;
    }
  }
}

// ---------- fallback pair (scratch inside out_mask region) ----------
__global__ __launch_bounds__(256) void mask_pack(
    const int* __restrict__ mask, unsigned long long* __restrict__ bits) {
  const size_t idx = (size_t)blockIdx.x * 256 + threadIdx.x;
  const unsigned long long b = __ballot(mask[idx] != 0);
  if ((threadIdx.x & 63) == 0) {
    const size_t w = idx >> 6;
    bits[(w & 63) * (size_t)N_NODES + (w >> 6)] = b;
  }
}
__global__ __launch_bounds__(256) void mask_copy(
    const int* __restrict__ mask, float* __restrict__ outm) {
  const size_t i4 = (size_t)blockIdx.x * 256 + threadIdx.x;
  const int4 mv = ((const int4*)mask)[i4];
  float4 o;
  o.x = mv.x ? 1.f : 0.f; o.y = mv.y ? 1.f : 0.f;
  o.z = mv.z ? 1.f : 0.f; o.w = mv.w ? 1.f : 0.f;
  ((float4*)outm)[i4] = o;
}

// ---------- Kernel A: xe-GEMM + fused hl/hr epilogue, B in MFMA-frag layout --
// xeB tile = (head k, ft, chunk c): 1024 bf16 = [h(2)][f(16)][quad(4)][j(8)],
// holding xe[m = c*64 + h*32 + quad*8 + j][col = k*64 + ft*16 + f].
__global__ __launch_bounds__(256) void xe_gemm(
    const float* __restrict__ x,
    const float* __restrict__ Ww,
    const float* __restrict__ Wb,
    const float* __restrict__ al,
    const float* __restrict__ ar,
    unsigned short* __restrict__ xeB,
    float* __restrict__ hl,             // [8][4096]
    float* __restrict__ hr) {
  __shared__ float As[32][65];
  __shared__ float Bs[32][65];
  const int tid = threadIdx.x;
  const int n0 = blockIdx.x * 64;
  const int j0 = blockIdx.y * 64;
  const int lr = tid >> 2;          // 0..63 row
  const int lc = (tid & 3) * 8;     // 0,8,16,24 k-offset
  const int ty = tid >> 4;
  const int tx = tid & 15;
  float c[4][4];
  #pragma unroll
  for (int i = 0; i < 4; ++i)
    #pragma unroll
    for (int j = 0; j < 4; ++j) c[i][j] = 0.f;

  for (int f0 = 0; f0 < F_IN; f0 += 32) {
    const float* ap = x  + (size_t)(n0 + lr) * F_IN + f0 + lc;
    const float* bp = Ww + (size_t)(j0 + lr) * F_IN + f0 + lc;
    const float4 a0 = *(const float4*)ap;
    const float4 a1 = *(const float4*)(ap + 4);
    const float4 b0 = *(const float4*)bp;
    const float4 b1 = *(const float4*)(bp + 4);
    __syncthreads();
    As[lc + 0][lr] = a0.x; As[lc + 1][lr] = a0.y;
    As[lc + 2][lr] = a0.z; As[lc + 3][lr] = a0.w;
    As[lc + 4][lr] = a1.x; As[lc + 5][lr] = a1.y;
    As[lc + 6][lr] = a1.z; As[lc + 7][lr] = a1.w;
    Bs[lc + 0][lr] = b0.x; Bs[lc + 1][lr] = b0.y;
    Bs[lc + 2][lr] = b0.z; Bs[lc + 3][lr] = b0.w;
    Bs[lc + 4][lr] = b1.x; Bs[lc + 5][lr] = b1.y;
    Bs[lc + 6][lr] = b1.z; Bs[lc + 7][lr] = b1.w;
    __syncthreads();
    #pragma unroll
    for (int kk = 0; kk < 32; ++kk) {
      const float4 av = *(const float4*)&As[kk][ty * 4];
      const float4 bv = *(const float4*)&Bs[kk][tx * 4];
      const float a4[4] = {av.x, av.y, av.z, av.w};
      const float b4[4] = {bv.x, bv.y, bv.z, bv.w};
      #pragma unroll
      for (int i = 0; i < 4; ++i)
        #pragma unroll
        for (int j = 0; j < 4; ++j) c[i][j] = fmaf(a4[i], b4[j], c[i][j]);
    }
  }
  // bias + frag-layout stores + hl/hr partials
  const float4 wb4 = *(const float4*)(Wb + j0 + tx * 4);
  const float4 al4 = *(const float4*)(al + j0 + tx * 4);
  const float4 ar4 = *(const float4*)(ar + j0 + tx * 4);
  const float wb[4] = {wb4.x, wb4.y, wb4.z, wb4.w};
  const float alv[4] = {al4.x, al4.y, al4.z, al4.w};
  const float arv[4] = {ar4.x, ar4.y, ar4.z, ar4.w};
  float v[4][4];
  float pl[4], pr[4];
  #pragma unroll
  for (int i = 0; i < 4; ++i) {
    float sl = 0.f, sr = 0.f;
    #pragma unroll
    for (int j = 0; j < 4; ++j) {
      v[i][j] = c[i][j] + wb[j];
      sl = fmaf(v[i][j], alv[j], sl);
      sr = fmaf(v[i][j], arv[j], sr);
    }
    pl[i] = sl; pr[i] = sr;
  }
  {
    // frag-layout address for this thread
    const int k   = blockIdx.y;         // head
    const int ft  = tx >> 2;
    const int fb  = (tx & 3) * 4;       // f base (4 consecutive f)
    const int cc  = blockIdx.x;         // chunk
    const int h_  = ty >> 3;
    const int qd  = (ty >> 1) & 3;
    const int jj0 = (ty & 1) * 4;       // 4 consecutive j (i-direction)
    unsigned short* tile = xeB + ((((size_t)(k * 4 + ft)) * 64 + cc) << 10)
                         + h_ * 512 + qd * 8 + jj0;
    #pragma unroll
    for (int j = 0; j < 4; ++j) {
      ushort4 pk;
      pk.x = f2bf(v[0][j]); pk.y = f2bf(v[1][j]);
      pk.z = f2bf(v[2][j]); pk.w = f2bf(v[3][j]);
      *(ushort4*)(tile + (fb + j) * 32) = pk;
    }
  }
  // reduce over the 16 tx lanes (contiguous within a wave)
  #pragma unroll
  for (int off = 8; off > 0; off >>= 1) {
    #pragma unroll
    for (int i = 0; i < 4; ++i) {
      pl[i] += __shfl_down(pl[i], off);
      pr[i] += __shfl_down(pr[i], off);
    }
  }
  if (tx == 0) {
    const int k = blockIdx.y;
    float4 o0 = {pl[0], pl[1], pl[2], pl[3]};
    float4 o1 = {pr[0], pr[1], pr[2], pr[3]};
    *(float4*)(hl + k * N_NODES + n0 + ty * 4) = o0;
    *(float4*)(hr + k * N_NODES + n0 + ty * 4) = o1;
  }
}

// ---------- Kernel B2: per-head hr max + E1=exp(hr), E2=exp(0.2*hr) ----------
__global__ __launch_bounds__(256) void hrmax_e_kernel(
    const float* __restrict__ hr, float* __restrict__ hrmax,
    float* __restrict__ E1, float* __restrict__ E2) {
  __shared__ float red[256];
  const int k = blockIdx.x;
  const int t = threadIdx.x;
  float m = -1e30f;
  for (int i = t; i < N_NODES; i += 256) m = fmaxf(m, hr[k * N_NODES + i]);
  red[t] = m;
  __syncthreads();
  for (int s = 128; s > 0; s >>= 1) {
    if (t < s) red[t] = fmaxf(red[t], red[t + s]);
    __syncthreads();
  }
  if (t == 0) hrmax[k] = red[0];
  for (int i = t; i < N_NODES; i += 256) {
    const float v = hr[k * N_NODES + i];
    E1[k * N_NODES + i] = __expf(v);
    E2[k * N_NODES + i] = __expf(NEG_SLOPE * v);
  }
}

// ---------- Kernel D: fused attention (exp-free inner loop, coalesced B) ----
// Block = 512 thr = 8 waves = one (16-row group, head); wave = 8 m-chunks.
// w = s>0 ? c1*E1[m] : c2*E2[m]  (sign via E1[m] > t, t = exp(-hl)); masked.
__global__ __launch_bounds__(512) void gat_attn(
    const unsigned long long* __restrict__ mbitsT,   // [64 c][4096 n]
    const float* __restrict__ hl,
    const float* __restrict__ hrmax,
    const float* __restrict__ E1,
    const float* __restrict__ E2,
    const unsigned short* __restrict__ xeB,
    float* __restrict__ out) {
  __shared__ float lds_acc[8][64][18];   // 36.9 KB
  __shared__ float lds_dp[8][16];
  const int t = threadIdx.x;
  const int w8 = t >> 6;                // wave 0..7 = m-eighth
  const int lane = t & 63;
  const int rg = blockIdx.x >> 3;       // row-group 0..255
  const int k  = blockIdx.x & 7;        // head
  const int n0 = rg * 16;
  const int row = lane & 15;
  const int quad = lane >> 4;
  const int q8 = quad * 8;

  const float hlv = hl[k * N_NODES + n0 + row];
  const float sM = hlv + hrmax[k];
  const float Mv = fmaxf(sM, NEG_SLOPE * sM);
  const float c1 = __expf(hlv - Mv);
  const float c2 = __expf(NEG_SLOPE * hlv - Mv);
  const float tt = __expf(-hlv);        // s>0  <=>  E1[m] > tt

  const float* E1_k = E1 + k * N_NODES;
  const float* E2_k = E2 + k * N_NODES;
  const unsigned long long* mrowT = mbitsT + n0 + row;   // + c*4096 per chunk
  const unsigned short* xeB_k = xeB + (((size_t)k * 4) << 16);  // 4 ft tiles*64KB

  floatx4 acc[4];
  #pragma unroll
  for (int ft = 0; ft < 4; ++ft) acc[ft] = (floatx4){0.f, 0.f, 0.f, 0.f};
  float dp = 0.f;

  const int c0 = w8 * 8;
  #pragma unroll 2
  for (int c = c0; c < c0 + 8; ++c) {
    const int base = c * 64;
    const unsigned long long mb = mrowT[(size_t)c * N_NODES];
    const unsigned mlo = (unsigned)(mb >> q8);
    const unsigned mhi = (unsigned)(mb >> (32 + q8));

    S8U4 a0, a1;
    {
      const float4 ea = *(const float4*)(E1_k + base + q8);
      const float4 eb = *(const float4*)(E1_k + base + q8 + 4);
      const float4 ga = *(const float4*)(E2_k + base + q8);
      const float4 gb = *(const float4*)(E2_k + base + q8 + 4);
      const float e1s[8] = {ea.x, ea.y, ea.z, ea.w, eb.x, eb.y, eb.z, eb.w};
      const float e2s[8] = {ga.x, ga.y, ga.z, ga.w, gb.x, gb.y, gb.z, gb.w};
      float w[8];
      #pragma unroll
      for (int j = 0; j < 8; ++j) {
        const float wv = (e1s[j] > tt) ? c1 * e1s[j] : c2 * e2s[j];
        const float wm = ((mlo >> j) & 1u) ? wv : 0.f;
        w[j] = wm; dp += wm;
      }
      #pragma unroll
      for (int p = 0; p < 4; ++p) {
        unsigned u0, u1;
        __builtin_memcpy(&u0, &w[2 * p], 4);
        __builtin_memcpy(&u1, &w[2 * p + 1], 4);
        a0.u[p] = ((u0 + 0x8000u) >> 16) | ((u1 + 0x8000u) & 0xFFFF0000u);
      }
    }
    {
      const float4 ea = *(const float4*)(E1_k + base + 32 + q8);
      const float4 eb = *(const float4*)(E1_k + base + 32 + q8 + 4);
      const float4 ga = *(const float4*)(E2_k + base + 32 + q8);
      const float4 gb = *(const float4*)(E2_k + base + 32 + q8 + 4);
      const float e1s[8] = {ea.x, ea.y, ea.z, ea.w, eb.x, eb.y, eb.z, eb.w};
      const float e2s[8] = {ga.x, ga.y, ga.z, ga.w, gb.x, gb.y, gb.z, gb.w};
      float w[8];
      #pragma unroll
      for (int j = 0; j < 8; ++j) {
        const float wv = (e1s[j] > tt) ? c1 * e1s[j] : c2 * e2s[j];
        const float wm = ((mhi >> j) & 1u) ? wv : 0.f;
        w[j] = wm; dp += wm;
      }
      #pragma unroll
      for (int p = 0; p < 4; ++p) {
        unsigned u0, u1;
        __builtin_memcpy(&u0, &w[2 * p], 4);
        __builtin_memcpy(&u1, &w[2 * p + 1], 4);
        a1.u[p] = ((u0 + 0x8000u) >> 16) | ((u1 + 0x8000u) & 0xFFFF0000u);
      }
    }
    #pragma unroll
    for (int ft = 0; ft < 4; ++ft) {
      // fully-coalesced 1 KB fragment loads
      const unsigned short* tile =
          xeB_k + ((((size_t)ft) * 64 + c) << 10) + row * 32 + q8;
      const short8 b0 = *(const short8*)tile;
      const short8 b1 = *(const short8*)(tile + 512);
      acc[ft] = __builtin_amdgcn_mfma_f32_16x16x32_bf16(a0.v, b0, acc[ft], 0, 0, 0);
      acc[ft] = __builtin_amdgcn_mfma_f32_16x16x32_bf16(a1.v, b1, acc[ft], 0, 0, 0);
    }
  }

  // dp: reduce over the 4 quads -> every lane holds total for row=lane&15
  dp += __shfl_xor(dp, 16);
  dp += __shfl_xor(dp, 32);

  // write partials
  #pragma unroll
  for (int i = 0; i < 16; ++i) lds_acc[w8][lane][i] = acc[i >> 2][i & 3];
  if (lane < 16) lds_dp[w8][lane] = dp;
  __syncthreads();

  // wave w8 finalizes output slots i = {2*w8, 2*w8+1} (same ft = w8>>1)
  const int ftq = w8 >> 1;
  float fa[2] = {0.f, 0.f};
  #pragma unroll
  for (int w2 = 0; w2 < 8; ++w2) {
    fa[0] += lds_acc[w2][lane][2 * w8];
    fa[1] += lds_acc[w2][lane][2 * w8 + 1];
  }
  #pragma unroll
  for (int j = 0; j < 2; ++j) {
    const int reg = (2 * w8 + j) & 3;
    const int row_o = quad * 4 + reg;
    float dpt = 0.f;
    #pragma unroll
    for (int w2 = 0; w2 < 8; ++w2) dpt += lds_dp[w2][row_o];
    float v = fa[j] / dpt;
    v = (v > 0.f) ? v : (__expf(v) - 1.f);
    v = (v > 0.f) ? v : (__expf(v) - 1.f);
    out[(size_t)(n0 + row_o) * KF + k * 64 + ftq * 16 + row] = v;
  }
}

// ---------- launcher ----------
extern "C" void kernel_launch(void* const* d_in, const int* in_sizes, int n_in,
                              void* d_out, int out_size, void* d_ws, size_t ws_size,
                              hipStream_t stream) {
  const float* x    = (const float*)d_in[0];   // (4096,256) fp32
  const float* Ww   = (const float*)d_in[1];   // (512,256)  fp32
  const float* Wb   = (const float*)d_in[2];   // (512,)     fp32
  const float* al   = (const float*)d_in[3];   // (1,8,64)   fp32
  const float* ar   = (const float*)d_in[4];   // (1,8,64)   fp32
  const int*   mask = (const int*)d_in[5];     // (1,4096,4096) int32

  float* out      = (float*)d_out;                    // (4096,512) fp32, 8 MB
  float* out_mask = out + (size_t)N_NODES * KF;       // (1,4096,4096) fp32, 64 MB

  const bool use_ws = (ws_size >= (8u << 20));
  char* scratch = use_ws ? (char*)d_ws : (char*)out_mask;
  unsigned short* xeB  = (unsigned short*)scratch;                 // 4 MB
  float*          hl   = (float*)(scratch + (4u << 20));           // 128 KB
  float*          hr   = hl + KH * N_NODES;                        // 128 KB
  float*          E1   = hr + KH * N_NODES;                        // 128 KB
  float*          E2   = E1 + KH * N_NODES;                        // 128 KB
  float*          hrmx = E2 + KH * N_NODES;                        // 32 B
  unsigned long long* mbitsT = (unsigned long long*)(scratch + (5u << 20)); // 2 MB
  // top of use: 7 MB

  // A: xe-GEMM + hl/hr fused epilogue (+ fragment-layout bf16 xe)
  dim3 ga(N_NODES / 64, KF / 64);
  xe_gemm<<<ga, 256, 0, stream>>>(x, Ww, Wb, al, ar, xeB, hl, hr);

  // B2: per-head hr max + E1/E2 precompute
  hrmax_e_kernel<<<KH, 256, 0, stream>>>(hr, hrmx, E1, E2);

  if (use_ws) {
    mask_fused<<<(N_NODES * (size_t)N_NODES) / 1024, 256, 0, stream>>>(
        mask, out_mask, mbitsT);
    gat_attn<<<256 * KH, 512, 0, stream>>>(mbitsT, hl, hrmx, E1, E2, xeB, out);
  } else {
    mask_pack<<<(N_NODES * (size_t)N_NODES) / 256, 256, 0, stream>>>(mask, mbitsT);
    gat_attn<<<256 * KH, 512, 0, stream>>>(mbitsT, hl, hrmx, E1, E2, xeB, out);
    mask_copy<<<(N_NODES * (size_t)N_NODES) / (4 * 256), 256, 0, stream>>>(mask, out_mask);
  }
}

// Round 9
// 258.573 us; speedup vs baseline: 3.8259x; 1.0357x over previous
//
#include <hip/hip_runtime.h>
#include <hip/hip_bf16.h>

// Problem constants (GAT_18176301597437)
#define N_NODES 4096
#define F_IN    256
#define KH      8
#define KF      512          // KH*FPH
#define NEG_SLOPE 0.2f

typedef __attribute__((ext_vector_type(8))) short short8;   // 8 bf16 = 4 VGPRs
typedef __attribute__((ext_vector_type(4))) float floatx4;  // MFMA C/D

union S8U4 { short8 v; unsigned u[4]; };

__device__ __forceinline__ unsigned short f2bf(float f) {
    __hip_bfloat16 h = __float2bfloat16(f);
    unsigned short u; __builtin_memcpy(&u, &h, 2);
    return u;
}
__device__ __forceinline__ unsigned packbf2(float w0, float w1) {
    float2 f2; f2.x = w0; f2.y = w1;
    __hip_bfloat162 h2 = __float22bfloat162_rn(f2);   // packed cvt on gfx950
    unsigned u; __builtin_memcpy(&u, &h2, 4);
    return u;
}

// ---------- mask_fused: one pass -> fp32 passthrough + TRANSPOSED bit-pack ----
// bits layout: word index = c*4096 + n   (c = m-chunk = (m>>6), n = row)
__global__ __launch_bounds__(256) void mask_fused(
    const int* __restrict__ mask, float* __restrict__ outm,
    unsigned long long* __restrict__ bits) {
  const size_t base = (size_t)blockIdx.x * 1024;
  const int tid = threadIdx.x;
  #pragma unroll
  for (int c = 0; c < 4; ++c) {
    const size_t e = base + c * 256 + tid;
    const int v = mask[e];
    outm[e] = v ? 1.f : 0.f;
    const unsigned long long b = __ballot(v != 0);
    if ((tid & 63) == 0) {
      const size_t w = e >> 6;
      bits[(w & 63) * (size_t)N_NODES + (w >> 6)] = b;
    }
  }
}

// ---------- fallback pair (scratch inside out_mask region) ----------
__global__ __launch_bounds__(256) void mask_pack(
    const int* __restrict__ mask, unsigned long long* __restrict__ bits) {
  const size_t idx = (size_t)blockIdx.x * 256 + threadIdx.x;
  const unsigned long long b = __ballot(mask[idx] != 0);
  if ((threadIdx.x & 63) == 0) {
    const size_t w = idx >> 6;
    bits[(w & 63) * (size_t)N_NODES + (w >> 6)] = b;
  }
}
__global__ __launch_bounds__(256) void mask_copy(
    const int* __restrict__ mask, float* __restrict__ outm) {
  const size_t i4 = (size_t)blockIdx.x * 256 + threadIdx.x;
  const int4 mv = ((const int4*)mask)[i4];
  float4 o;
  o.x = mv.x ? 1.f : 0.f; o.y = mv.y ? 1.f : 0.f;
  o.z = mv.z ? 1.f : 0.f; o.w = mv.w ? 1.f : 0.f;
  ((float4*)outm)[i4] = o;
}

// ---------- Kernel A: xe-GEMM + fused hl/E1/E2/blockmax epilogue -------------
// xeB tile = (head k, ft, chunk c): 1024 bf16 = [h(2)][f(16)][quad(4)][j(8)].
__global__ __launch_bounds__(256) void xe_gemm(
    const float* __restrict__ x,
    const float* __restrict__ Ww,
    const float* __restrict__ Wb,
    const float* __restrict__ al,
    const float* __restrict__ ar,
    unsigned short* __restrict__ xeB,
    float* __restrict__ hl,             // [8][4096]
    float* __restrict__ E1,             // [8][4096] = exp(hr)
    float* __restrict__ E2,             // [8][4096] = exp(0.2*hr)
    float* __restrict__ bmax) {         // [8][64] per-block hr max
  __shared__ float As[32][65];
  __shared__ float Bs[32][65];
  __shared__ float redmax[4];
  const int tid = threadIdx.x;
  const int n0 = blockIdx.x * 64;
  const int j0 = blockIdx.y * 64;
  const int lr = tid >> 2;          // 0..63 row
  const int lc = (tid & 3) * 8;     // 0,8,16,24 k-offset
  const int ty = tid >> 4;
  const int tx = tid & 15;
  float c[4][4];
  #pragma unroll
  for (int i = 0; i < 4; ++i)
    #pragma unroll
    for (int j = 0; j < 4; ++j) c[i][j] = 0.f;

  for (int f0 = 0; f0 < F_IN; f0 += 32) {
    const float* ap = x  + (size_t)(n0 + lr) * F_IN + f0 + lc;
    const float* bp = Ww + (size_t)(j0 + lr) * F_IN + f0 + lc;
    const float4 a0 = *(const float4*)ap;
    const float4 a1 = *(const float4*)(ap + 4);
    const float4 b0 = *(const float4*)bp;
    const float4 b1 = *(const float4*)(bp + 4);
    __syncthreads();
    As[lc + 0][lr] = a0.x; As[lc + 1][lr] = a0.y;
    As[lc + 2][lr] = a0.z; As[lc + 3][lr] = a0.w;
    As[lc + 4][lr] = a1.x; As[lc + 5][lr] = a1.y;
    As[lc + 6][lr] = a1.z; As[lc + 7][lr] = a1.w;
    Bs[lc + 0][lr] = b0.x; Bs[lc + 1][lr] = b0.y;
    Bs[lc + 2][lr] = b0.z; Bs[lc + 3][lr] = b0.w;
    Bs[lc + 4][lr] = b1.x; Bs[lc + 5][lr] = b1.y;
    Bs[lc + 6][lr] = b1.z; Bs[lc + 7][lr] = b1.w;
    __syncthreads();
    #pragma unroll
    for (int kk = 0; kk < 32; ++kk) {
      const float4 av = *(const float4*)&As[kk][ty * 4];
      const float4 bv = *(const float4*)&Bs[kk][tx * 4];
      const float a4[4] = {av.x, av.y, av.z, av.w};
      const float b4[4] = {bv.x, bv.y, bv.z, bv.w};
      #pragma unroll
      for (int i = 0; i < 4; ++i)
        #pragma unroll
        for (int j = 0; j < 4; ++j) c[i][j] = fmaf(a4[i], b4[j], c[i][j]);
    }
  }
  // bias + frag-layout stores + hl/hr partials
  const float4 wb4 = *(const float4*)(Wb + j0 + tx * 4);
  const float4 al4 = *(const float4*)(al + j0 + tx * 4);
  const float4 ar4 = *(const float4*)(ar + j0 + tx * 4);
  const float wb[4] = {wb4.x, wb4.y, wb4.z, wb4.w};
  const float alv[4] = {al4.x, al4.y, al4.z, al4.w};
  const float arv[4] = {ar4.x, ar4.y, ar4.z, ar4.w};
  float v[4][4];
  float pl[4], pr[4];
  #pragma unroll
  for (int i = 0; i < 4; ++i) {
    float sl = 0.f, sr = 0.f;
    #pragma unroll
    for (int j = 0; j < 4; ++j) {
      v[i][j] = c[i][j] + wb[j];
      sl = fmaf(v[i][j], alv[j], sl);
      sr = fmaf(v[i][j], arv[j], sr);
    }
    pl[i] = sl; pr[i] = sr;
  }
  {
    const int k   = blockIdx.y;
    const int ft  = tx >> 2;
    const int fb  = (tx & 3) * 4;
    const int cc  = blockIdx.x;
    const int h_  = ty >> 3;
    const int qd  = (ty >> 1) & 3;
    const int jj0 = (ty & 1) * 4;
    unsigned short* tile = xeB + ((((size_t)(k * 4 + ft)) * 64 + cc) << 10)
                         + h_ * 512 + qd * 8 + jj0;
    #pragma unroll
    for (int j = 0; j < 4; ++j) {
      ushort4 pk;
      pk.x = f2bf(v[0][j]); pk.y = f2bf(v[1][j]);
      pk.z = f2bf(v[2][j]); pk.w = f2bf(v[3][j]);
      *(ushort4*)(tile + (fb + j) * 32) = pk;
    }
  }
  // reduce over the 16 tx lanes
  #pragma unroll
  for (int off = 8; off > 0; off >>= 1) {
    #pragma unroll
    for (int i = 0; i < 4; ++i) {
      pl[i] += __shfl_down(pl[i], off);
      pr[i] += __shfl_down(pr[i], off);
    }
  }
  if (tx == 0) {
    const int k = blockIdx.y;
    float4 o0 = {pl[0], pl[1], pl[2], pl[3]};
    *(float4*)(hl + k * N_NODES + n0 + ty * 4) = o0;
    float4 e1 = {__expf(pr[0]), __expf(pr[1]), __expf(pr[2]), __expf(pr[3])};
    float4 e2 = {__expf(NEG_SLOPE * pr[0]), __expf(NEG_SLOPE * pr[1]),
                 __expf(NEG_SLOPE * pr[2]), __expf(NEG_SLOPE * pr[3])};
    *(float4*)(E1 + k * N_NODES + n0 + ty * 4) = e1;
    *(float4*)(E2 + k * N_NODES + n0 + ty * 4) = e2;
  }
  // block max of hr (for softmax shift): only tx==0 lanes hold full sums
  float bm = (tx == 0)
      ? fmaxf(fmaxf(pr[0], pr[1]), fmaxf(pr[2], pr[3])) : -1e30f;
  bm = fmaxf(bm, __shfl_xor(bm, 16));
  bm = fmaxf(bm, __shfl_xor(bm, 32));
  if ((tid & 63) == 0) redmax[tid >> 6] = bm;
  __syncthreads();
  if (tid == 0) {
    bmax[blockIdx.y * 64 + blockIdx.x] =
        fmaxf(fmaxf(redmax[0], redmax[1]), fmaxf(redmax[2], redmax[3]));
  }
}

// ---------- Kernel D: fused attention ----------------------------------------
// Block = 512 thr = 8 waves = one (16-row group, head); wave = 8 m-chunks.
// w = max(c1*E1[m], c2*E2[m]) (lrelu-exp identity), masked, packed via
// v_cvt_pk. dp computed by MFMA against a ones-B fragment (lands in the same
// lane/reg as the C rows -> division needs no shuffles).
__global__ __launch_bounds__(512) void gat_attn(
    const unsigned long long* __restrict__ mbitsT,   // [64 c][4096 n]
    const float* __restrict__ hl,
    const float* __restrict__ bmax,                  // [8][64]
    const float* __restrict__ E1,
    const float* __restrict__ E2,
    const unsigned short* __restrict__ xeB,
    float* __restrict__ out) {
  __shared__ float lds_acc[8][64][20];   // 40 KB (16 C slots + 4 dp slots)
  const int t = threadIdx.x;
  const int w8 = t >> 6;                // wave 0..7 = m-eighth
  const int lane = t & 63;
  const int k  = blockIdx.x >> 8;       // same-k grouping for L2 locality
  const int rg = blockIdx.x & 255;
  const int n0 = rg * 16;
  const int row = lane & 15;
  const int quad = lane >> 4;
  const int q8 = quad * 8;

  // hrmax from the 64 per-block maxes
  float hm = bmax[k * 64 + lane];
  #pragma unroll
  for (int o = 1; o < 64; o <<= 1) hm = fmaxf(hm, __shfl_xor(hm, o));

  const float hlv = hl[k * N_NODES + n0 + row];
  const float sM = hlv + hm;
  const float Mv = fmaxf(sM, NEG_SLOPE * sM);   // >= every score in this row
  const float c1 = __expf(hlv - Mv);
  const float c2 = __expf(NEG_SLOPE * hlv - Mv);

  const float* E1_k = E1 + k * N_NODES;
  const float* E2_k = E2 + k * N_NODES;
  const unsigned long long* mrowT = mbitsT + n0 + row;
  const unsigned short* xeB_k = xeB + (((size_t)k * 4) << 16);

  short8 ones;
  #pragma unroll
  for (int i = 0; i < 8; ++i) ones[i] = (short)0x3F80;   // bf16 1.0

  floatx4 acc[4];
  #pragma unroll
  for (int ft = 0; ft < 4; ++ft) acc[ft] = (floatx4){0.f, 0.f, 0.f, 0.f};
  floatx4 accdp = (floatx4){0.f, 0.f, 0.f, 0.f};

  const int c0 = w8 * 8;
  #pragma unroll 2
  for (int cc = c0; cc < c0 + 8; ++cc) {
    const int base = cc * 64;
    const unsigned long long mb = mrowT[(size_t)cc * N_NODES];
    const unsigned mlo = (unsigned)(mb >> q8);
    const unsigned mhi = (unsigned)(mb >> (32 + q8));

    S8U4 a0, a1;
    {
      const float4 ea = *(const float4*)(E1_k + base + q8);
      const float4 eb = *(const float4*)(E1_k + base + q8 + 4);
      const float4 ga = *(const float4*)(E2_k + base + q8);
      const float4 gb = *(const float4*)(E2_k + base + q8 + 4);
      const float e1s[8] = {ea.x, ea.y, ea.z, ea.w, eb.x, eb.y, eb.z, eb.w};
      const float e2s[8] = {ga.x, ga.y, ga.z, ga.w, gb.x, gb.y, gb.z, gb.w};
      #pragma unroll
      for (int p = 0; p < 4; ++p) {
        float w0 = fmaxf(c1 * e1s[2 * p],     c2 * e2s[2 * p]);
        float w1 = fmaxf(c1 * e1s[2 * p + 1], c2 * e2s[2 * p + 1]);
        w0 = ((mlo >> (2 * p)) & 1u)     ? w0 : 0.f;
        w1 = ((mlo >> (2 * p + 1)) & 1u) ? w1 : 0.f;
        a0.u[p] = packbf2(w0, w1);
      }
    }
    {
      const float4 ea = *(const float4*)(E1_k + base + 32 + q8);
      const float4 eb = *(const float4*)(E1_k + base + 32 + q8 + 4);
      const float4 ga = *(const float4*)(E2_k + base + 32 + q8);
      const float4 gb = *(const float4*)(E2_k + base + 32 + q8 + 4);
      const float e1s[8] = {ea.x, ea.y, ea.z, ea.w, eb.x, eb.y, eb.z, eb.w};
      const float e2s[8] = {ga.x, ga.y, ga.z, ga.w, gb.x, gb.y, gb.z, gb.w};
      #pragma unroll
      for (int p = 0; p < 4; ++p) {
        float w0 = fmaxf(c1 * e1s[2 * p],     c2 * e2s[2 * p]);
        float w1 = fmaxf(c1 * e1s[2 * p + 1], c2 * e2s[2 * p + 1]);
        w0 = ((mhi >> (2 * p)) & 1u)     ? w0 : 0.f;
        w1 = ((mhi >> (2 * p + 1)) & 1u) ? w1 : 0.f;
        a1.u[p] = packbf2(w0, w1);
      }
    }
    // dp row-sums via ones-B (same rounded fragments as the numerator)
    accdp = __builtin_amdgcn_mfma_f32_16x16x32_bf16(a0.v, ones, accdp, 0, 0, 0);
    accdp = __builtin_amdgcn_mfma_f32_16x16x32_bf16(a1.v, ones, accdp, 0, 0, 0);
    #pragma unroll
    for (int ft = 0; ft < 4; ++ft) {
      const unsigned short* tile =
          xeB_k + ((((size_t)ft) * 64 + cc) << 10) + row * 32 + q8;
      const short8 b0 = *(const short8*)tile;
      const short8 b1 = *(const short8*)(tile + 512);
      acc[ft] = __builtin_amdgcn_mfma_f32_16x16x32_bf16(a0.v, b0, acc[ft], 0, 0, 0);
      acc[ft] = __builtin_amdgcn_mfma_f32_16x16x32_bf16(a1.v, b1, acc[ft], 0, 0, 0);
    }
  }

  // write partials (16 C slots + 4 dp slots per lane)
  #pragma unroll
  for (int i = 0; i < 16; ++i) lds_acc[w8][lane][i] = acc[i >> 2][i & 3];
  #pragma unroll
  for (int i = 0; i < 4; ++i) lds_acc[w8][lane][16 + i] = accdp[i];
  __syncthreads();

  // wave w8 finalizes output slots {2*w8, 2*w8+1}
  const int ftq = w8 >> 1;
  #pragma unroll
  for (int j = 0; j < 2; ++j) {
    const int sl = 2 * w8 + j;
    const int reg = sl & 3;
    const int row_o = quad * 4 + reg;
    float fa = 0.f, dpt = 0.f;
    #pragma unroll
    for (int w2 = 0; w2 < 8; ++w2) {
      fa  += lds_acc[w2][lane][sl];
      dpt += lds_acc[w2][lane][16 + reg];
    }
    float v = fa / dpt;
    v = (v > 0.f) ? v : (__expf(v) - 1.f);
    v = (v > 0.f) ? v : (__expf(v) - 1.f);
    out[(size_t)(n0 + row_o) * KF + k * 64 + ftq * 16 + row] = v;
  }
}

// ---------- launcher ----------
extern "C" void kernel_launch(void* const* d_in, const int* in_sizes, int n_in,
                              void* d_out, int out_size, void* d_ws, size_t ws_size,
                              hipStream_t stream) {
  const float* x    = (const float*)d_in[0];   // (4096,256) fp32
  const float* Ww   = (const float*)d_in[1];   // (512,256)  fp32
  const float* Wb   = (const float*)d_in[2];   // (512,)     fp32
  const float* al   = (const float*)d_in[3];   // (1,8,64)   fp32
  const float* ar   = (const float*)d_in[4];   // (1,8,64)   fp32
  const int*   mask = (const int*)d_in[5];     // (1,4096,4096) int32

  float* out      = (float*)d_out;                    // (4096,512) fp32, 8 MB
  float* out_mask = out + (size_t)N_NODES * KF;       // (1,4096,4096) fp32, 64 MB

  const bool use_ws = (ws_size >= (8u << 20));
  char* scratch = use_ws ? (char*)d_ws : (char*)out_mask;
  unsigned short* xeB  = (unsigned short*)scratch;                 // 4 MB
  float*          hl   = (float*)(scratch + (4u << 20));           // 128 KB
  float*          E1   = hl + KH * N_NODES;                        // 128 KB
  float*          E2   = E1 + KH * N_NODES;                        // 128 KB
  float*          bmax = E2 + KH * N_NODES;                        // 2 KB
  unsigned long long* mbitsT = (unsigned long long*)(scratch + (5u << 20)); // 2 MB
  // top of use: 7 MB

  // A: xe-GEMM + hl/E1/E2/blockmax fused epilogue (+ fragment-layout bf16 xe)
  dim3 ga(N_NODES / 64, KF / 64);
  xe_gemm<<<ga, 256, 0, stream>>>(x, Ww, Wb, al, ar, xeB, hl, E1, E2, bmax);

  if (use_ws) {
    mask_fused<<<(N_NODES * (size_t)N_NODES) / 1024, 256, 0, stream>>>(
        mask, out_mask, mbitsT);
    gat_attn<<<256 * KH, 512, 0, stream>>>(mbitsT, hl, bmax, E1, E2, xeB, out);
  } else {
    mask_pack<<<(N_NODES * (size_t)N_NODES) / 256, 256, 0, stream>>>(mask, mbitsT);
    gat_attn<<<256 * KH, 512, 0, stream>>>(mbitsT, hl, bmax, E1, E2, xeB, out);
    mask_copy<<<(N_NODES * (size_t)N_NODES) / (4 * 256), 256, 0, stream>>>(mask, out_mask);
  }
}

// Round 10
// 244.246 us; speedup vs baseline: 4.0503x; 1.0587x over previous
//
#include <hip/hip_runtime.h>
#include <hip/hip_bf16.h>

// Problem constants (GAT_18176301597437)
#define N_NODES 4096
#define F_IN    256
#define KH      8
#define KF      512          // KH*FPH
#define NEG_SLOPE 0.2f

typedef __attribute__((ext_vector_type(8))) short short8;   // 8 bf16 = 4 VGPRs
typedef __attribute__((ext_vector_type(4))) float floatx4;  // MFMA C/D

union S8U4 { short8 v; unsigned u[4]; };

__device__ __forceinline__ unsigned short f2bf(float f) {
    __hip_bfloat16 h = __float2bfloat16(f);
    unsigned short u; __builtin_memcpy(&u, &h, 2);
    return u;
}
__device__ __forceinline__ unsigned packbf2(float w0, float w1) {
    float2 f2; f2.x = w0; f2.y = w1;
    __hip_bfloat162 h2 = __float22bfloat162_rn(f2);
    unsigned u; __builtin_memcpy(&u, &h2, 4);
    return u;
}
__device__ __forceinline__ float asf(unsigned u) {
    float f; __builtin_memcpy(&f, &u, 4);
    return f;
}

// ---------- mask_fused: one pass -> fp32 passthrough + TRANSPOSED bit-pack ----
__global__ __launch_bounds__(256) void mask_fused(
    const int* __restrict__ mask, float* __restrict__ outm,
    unsigned long long* __restrict__ bits) {
  const size_t base = (size_t)blockIdx.x * 1024;
  const int tid = threadIdx.x;
  #pragma unroll
  for (int c = 0; c < 4; ++c) {
    const size_t e = base + c * 256 + tid;
    const int v = mask[e];
    outm[e] = v ? 1.f : 0.f;
    const unsigned long long b = __ballot(v != 0);
    if ((tid & 63) == 0) {
      const size_t w = e >> 6;
      bits[(w & 63) * (size_t)N_NODES + (w >> 6)] = b;
    }
  }
}

// ---------- fallback pair (scratch inside out_mask region) ----------
__global__ __launch_bounds__(256) void mask_pack(
    const int* __restrict__ mask, unsigned long long* __restrict__ bits) {
  const size_t idx = (size_t)blockIdx.x * 256 + threadIdx.x;
  const unsigned long long b = __ballot(mask[idx] != 0);
  if ((threadIdx.x & 63) == 0) {
    const size_t w = idx >> 6;
    bits[(w & 63) * (size_t)N_NODES + (w >> 6)] = b;
  }
}
__global__ __launch_bounds__(256) void mask_copy(
    const int* __restrict__ mask, float* __restrict__ outm) {
  const size_t i4 = (size_t)blockIdx.x * 256 + threadIdx.x;
  const int4 mv = ((const int4*)mask)[i4];
  float4 o;
  o.x = mv.x ? 1.f : 0.f; o.y = mv.y ? 1.f : 0.f;
  o.z = mv.z ? 1.f : 0.f; o.w = mv.w ? 1.f : 0.f;
  ((float4*)outm)[i4] = o;
}

// ---------- Kernel A: xe-GEMM + fused hl/E12/blockmax epilogue ---------------
// xeB tile = (head k, ft, chunk c): 1024 bf16 = [h(2)][f(16)][quad(4)][j(8)].
// E12[k][n] = packed (bf16 exp(hr) | bf16 exp(0.2*hr) << 16)
__global__ __launch_bounds__(256) void xe_gemm(
    const float* __restrict__ x,
    const float* __restrict__ Ww,
    const float* __restrict__ Wb,
    const float* __restrict__ al,
    const float* __restrict__ ar,
    unsigned short* __restrict__ xeB,
    float* __restrict__ hl,             // [8][4096]
    unsigned* __restrict__ E12,         // [8][4096]
    float* __restrict__ bmax) {         // [8][64]
  __shared__ float As[32][65];
  __shared__ float Bs[32][65];
  __shared__ float redmax[4];
  const int tid = threadIdx.x;
  const int n0 = blockIdx.x * 64;
  const int j0 = blockIdx.y * 64;
  const int lr = tid >> 2;
  const int lc = (tid & 3) * 8;
  const int ty = tid >> 4;
  const int tx = tid & 15;
  float c[4][4];
  #pragma unroll
  for (int i = 0; i < 4; ++i)
    #pragma unroll
    for (int j = 0; j < 4; ++j) c[i][j] = 0.f;

  for (int f0 = 0; f0 < F_IN; f0 += 32) {
    const float* ap = x  + (size_t)(n0 + lr) * F_IN + f0 + lc;
    const float* bp = Ww + (size_t)(j0 + lr) * F_IN + f0 + lc;
    const float4 a0 = *(const float4*)ap;
    const float4 a1 = *(const float4*)(ap + 4);
    const float4 b0 = *(const float4*)bp;
    const float4 b1 = *(const float4*)(bp + 4);
    __syncthreads();
    As[lc + 0][lr] = a0.x; As[lc + 1][lr] = a0.y;
    As[lc + 2][lr] = a0.z; As[lc + 3][lr] = a0.w;
    As[lc + 4][lr] = a1.x; As[lc + 5][lr] = a1.y;
    As[lc + 6][lr] = a1.z; As[lc + 7][lr] = a1.w;
    Bs[lc + 0][lr] = b0.x; Bs[lc + 1][lr] = b0.y;
    Bs[lc + 2][lr] = b0.z; Bs[lc + 3][lr] = b0.w;
    Bs[lc + 4][lr] = b1.x; Bs[lc + 5][lr] = b1.y;
    Bs[lc + 6][lr] = b1.z; Bs[lc + 7][lr] = b1.w;
    __syncthreads();
    #pragma unroll
    for (int kk = 0; kk < 32; ++kk) {
      const float4 av = *(const float4*)&As[kk][ty * 4];
      const float4 bv = *(const float4*)&Bs[kk][tx * 4];
      const float a4[4] = {av.x, av.y, av.z, av.w};
      const float b4[4] = {bv.x, bv.y, bv.z, bv.w};
      #pragma unroll
      for (int i = 0; i < 4; ++i)
        #pragma unroll
        for (int j = 0; j < 4; ++j) c[i][j] = fmaf(a4[i], b4[j], c[i][j]);
    }
  }
  const float4 wb4 = *(const float4*)(Wb + j0 + tx * 4);
  const float4 al4 = *(const float4*)(al + j0 + tx * 4);
  const float4 ar4 = *(const float4*)(ar + j0 + tx * 4);
  const float wb[4] = {wb4.x, wb4.y, wb4.z, wb4.w};
  const float alv[4] = {al4.x, al4.y, al4.z, al4.w};
  const float arv[4] = {ar4.x, ar4.y, ar4.z, ar4.w};
  float v[4][4];
  float pl[4], pr[4];
  #pragma unroll
  for (int i = 0; i < 4; ++i) {
    float sl = 0.f, sr = 0.f;
    #pragma unroll
    for (int j = 0; j < 4; ++j) {
      v[i][j] = c[i][j] + wb[j];
      sl = fmaf(v[i][j], alv[j], sl);
      sr = fmaf(v[i][j], arv[j], sr);
    }
    pl[i] = sl; pr[i] = sr;
  }
  {
    const int k   = blockIdx.y;
    const int ft  = tx >> 2;
    const int fb  = (tx & 3) * 4;
    const int cc  = blockIdx.x;
    const int h_  = ty >> 3;
    const int qd  = (ty >> 1) & 3;
    const int jj0 = (ty & 1) * 4;
    unsigned short* tile = xeB + ((((size_t)(k * 4 + ft)) * 64 + cc) << 10)
                         + h_ * 512 + qd * 8 + jj0;
    #pragma unroll
    for (int j = 0; j < 4; ++j) {
      ushort4 pk;
      pk.x = f2bf(v[0][j]); pk.y = f2bf(v[1][j]);
      pk.z = f2bf(v[2][j]); pk.w = f2bf(v[3][j]);
      *(ushort4*)(tile + (fb + j) * 32) = pk;
    }
  }
  #pragma unroll
  for (int off = 8; off > 0; off >>= 1) {
    #pragma unroll
    for (int i = 0; i < 4; ++i) {
      pl[i] += __shfl_down(pl[i], off);
      pr[i] += __shfl_down(pr[i], off);
    }
  }
  if (tx == 0) {
    const int k = blockIdx.y;
    float4 o0 = {pl[0], pl[1], pl[2], pl[3]};
    *(float4*)(hl + k * N_NODES + n0 + ty * 4) = o0;
    uint4 ev;
    ev.x = (unsigned)f2bf(__expf(pr[0])) | ((unsigned)f2bf(__expf(NEG_SLOPE * pr[0])) << 16);
    ev.y = (unsigned)f2bf(__expf(pr[1])) | ((unsigned)f2bf(__expf(NEG_SLOPE * pr[1])) << 16);
    ev.z = (unsigned)f2bf(__expf(pr[2])) | ((unsigned)f2bf(__expf(NEG_SLOPE * pr[2])) << 16);
    ev.w = (unsigned)f2bf(__expf(pr[3])) | ((unsigned)f2bf(__expf(NEG_SLOPE * pr[3])) << 16);
    *(uint4*)(E12 + k * N_NODES + n0 + ty * 4) = ev;
  }
  float bm = (tx == 0)
      ? fmaxf(fmaxf(pr[0], pr[1]), fmaxf(pr[2], pr[3])) : -1e30f;
  bm = fmaxf(bm, __shfl_xor(bm, 16));
  bm = fmaxf(bm, __shfl_xor(bm, 32));
  if ((tid & 63) == 0) redmax[tid >> 6] = bm;
  __syncthreads();
  if (tid == 0) {
    bmax[blockIdx.y * 64 + blockIdx.x] =
        fmaxf(fmaxf(redmax[0], redmax[1]), fmaxf(redmax[2], redmax[3]));
  }
}

// ---------- Kernel D: fused attention, software-pipelined --------------------
// Block = 256 thr = 4 waves = one (16-row group, head); wave = 16 m-chunks.
// Pipeline: prefetch E12+mask for chunk c+1 in registers; B-loads for chunk c
// issue BEFORE the w-compute that covers their L2 latency.
__global__ __launch_bounds__(256, 4) void gat_attn(
    const unsigned long long* __restrict__ mbitsT,   // [64 c][4096 n]
    const float* __restrict__ hl,
    const float* __restrict__ bmax,                  // [8][64]
    const unsigned* __restrict__ E12,                // [8][4096] bf16 pair
    const unsigned short* __restrict__ xeB,
    float* __restrict__ out) {
  __shared__ float lds_acc[4][64][20];   // 20 KB
  const int t = threadIdx.x;
  const int w4 = t >> 6;                // wave 0..3 = m-quarter
  const int lane = t & 63;
  const int k  = blockIdx.x >> 8;       // same-k grouping for L2 locality
  const int rg = blockIdx.x & 255;
  const int n0 = rg * 16;
  const int row = lane & 15;
  const int quad = lane >> 4;
  const int q8 = quad * 8;

  float hm = bmax[k * 64 + lane];
  #pragma unroll
  for (int o = 1; o < 64; o <<= 1) hm = fmaxf(hm, __shfl_xor(hm, o));

  const float hlv = hl[k * N_NODES + n0 + row];
  const float sM = hlv + hm;
  const float Mv = fmaxf(sM, NEG_SLOPE * sM);
  const float c1 = __expf(hlv - Mv);
  const float c2 = __expf(NEG_SLOPE * hlv - Mv);

  const unsigned* E12_k = E12 + k * N_NODES;
  const unsigned long long* mrowT = mbitsT + n0 + row;
  const unsigned short* xeB_k = xeB + (((size_t)k * 4) << 16);

  short8 ones;
  #pragma unroll
  for (int i = 0; i < 8; ++i) ones[i] = (short)0x3F80;   // bf16 1.0

  floatx4 acc[4];
  #pragma unroll
  for (int ft = 0; ft < 4; ++ft) acc[ft] = (floatx4){0.f, 0.f, 0.f, 0.f};
  floatx4 accdp = (floatx4){0.f, 0.f, 0.f, 0.f};

  const int c0 = w4 * 16;
  const int cEnd = c0 + 16;

  // prefetch chunk c0 (E12: lo 8 pairs + hi 8 pairs; mask word)
  uint4 pA, pB, pC, pD;
  unsigned long long pM;
  {
    const unsigned* pe = E12_k + c0 * 64 + q8;
    pA = *(const uint4*)pe;       pB = *(const uint4*)(pe + 4);
    pC = *(const uint4*)(pe + 32); pD = *(const uint4*)(pe + 36);
    pM = mrowT[(size_t)c0 * N_NODES];
  }

  for (int cc = c0; cc < cEnd; ++cc) {
    // ---- issue B loads for this chunk (consumed after w-compute) ----
    short8 b0, b1, b2, b3, b4, b5, b6, b7;
    {
      const unsigned short* tb = xeB_k + (((size_t)cc) << 10) + row * 32 + q8;
      b0 = *(const short8*)tb;              b1 = *(const short8*)(tb + 512);
      b2 = *(const short8*)(tb + (64 << 10));      b3 = *(const short8*)(tb + (64 << 10) + 512);
      b4 = *(const short8*)(tb + (128 << 10));     b5 = *(const short8*)(tb + (128 << 10) + 512);
      b6 = *(const short8*)(tb + (192 << 10));     b7 = *(const short8*)(tb + (192 << 10) + 512);
    }
    // ---- stash current E/mask, prefetch next chunk ----
    const uint4 eL0 = pA, eL1 = pB, eH0 = pC, eH1 = pD;
    const unsigned long long mb = pM;
    if (cc + 1 < cEnd) {
      const unsigned* pe = E12_k + (cc + 1) * 64 + q8;
      pA = *(const uint4*)pe;       pB = *(const uint4*)(pe + 4);
      pC = *(const uint4*)(pe + 32); pD = *(const uint4*)(pe + 36);
      pM = mrowT[(size_t)(cc + 1) * N_NODES];
    }
    // ---- w-compute (covers B-load latency) ----
    const unsigned mlo = (unsigned)(mb >> q8);
    const unsigned mhi = (unsigned)(mb >> (32 + q8));
    S8U4 a0, a1;
    {
      const unsigned e[8] = {eL0.x, eL0.y, eL0.z, eL0.w, eL1.x, eL1.y, eL1.z, eL1.w};
      #pragma unroll
      for (int p = 0; p < 4; ++p) {
        const unsigned u0 = e[2 * p], u1 = e[2 * p + 1];
        float w0 = fmaxf(c1 * asf(u0 << 16), c2 * asf(u0 & 0xFFFF0000u));
        float w1 = fmaxf(c1 * asf(u1 << 16), c2 * asf(u1 & 0xFFFF0000u));
        w0 = ((mlo >> (2 * p)) & 1u)     ? w0 : 0.f;
        w1 = ((mlo >> (2 * p + 1)) & 1u) ? w1 : 0.f;
        a0.u[p] = packbf2(w0, w1);
      }
    }
    {
      const unsigned e[8] = {eH0.x, eH0.y, eH0.z, eH0.w, eH1.x, eH1.y, eH1.z, eH1.w};
      #pragma unroll
      for (int p = 0; p < 4; ++p) {
        const unsigned u0 = e[2 * p], u1 = e[2 * p + 1];
        float w0 = fmaxf(c1 * asf(u0 << 16), c2 * asf(u0 & 0xFFFF0000u));
        float w1 = fmaxf(c1 * asf(u1 << 16), c2 * asf(u1 & 0xFFFF0000u));
        w0 = ((mhi >> (2 * p)) & 1u)     ? w0 : 0.f;
        w1 = ((mhi >> (2 * p + 1)) & 1u) ? w1 : 0.f;
        a1.u[p] = packbf2(w0, w1);
      }
    }
    // ---- MFMAs ----
    accdp = __builtin_amdgcn_mfma_f32_16x16x32_bf16(a0.v, ones, accdp, 0, 0, 0);
    accdp = __builtin_amdgcn_mfma_f32_16x16x32_bf16(a1.v, ones, accdp, 0, 0, 0);
    acc[0] = __builtin_amdgcn_mfma_f32_16x16x32_bf16(a0.v, b0, acc[0], 0, 0, 0);
    acc[0] = __builtin_amdgcn_mfma_f32_16x16x32_bf16(a1.v, b1, acc[0], 0, 0, 0);
    acc[1] = __builtin_amdgcn_mfma_f32_16x16x32_bf16(a0.v, b2, acc[1], 0, 0, 0);
    acc[1] = __builtin_amdgcn_mfma_f32_16x16x32_bf16(a1.v, b3, acc[1], 0, 0, 0);
    acc[2] = __builtin_amdgcn_mfma_f32_16x16x32_bf16(a0.v, b4, acc[2], 0, 0, 0);
    acc[2] = __builtin_amdgcn_mfma_f32_16x16x32_bf16(a1.v, b5, acc[2], 0, 0, 0);
    acc[3] = __builtin_amdgcn_mfma_f32_16x16x32_bf16(a0.v, b6, acc[3], 0, 0, 0);
    acc[3] = __builtin_amdgcn_mfma_f32_16x16x32_bf16(a1.v, b7, acc[3], 0, 0, 0);
  }

  // write partials (16 C slots + 4 dp slots per lane)
  #pragma unroll
  for (int i = 0; i < 16; ++i) lds_acc[w4][lane][i] = acc[i >> 2][i & 3];
  #pragma unroll
  for (int i = 0; i < 4; ++i) lds_acc[w4][lane][16 + i] = accdp[i];
  __syncthreads();

  // wave w4 finalizes ft = w4 (slots 4*w4 .. 4*w4+3; reg j -> row quad*4+j)
  #pragma unroll
  for (int j = 0; j < 4; ++j) {
    const int sl = 4 * w4 + j;
    const int row_o = quad * 4 + j;
    float fa = 0.f, dpt = 0.f;
    #pragma unroll
    for (int w2 = 0; w2 < 4; ++w2) {
      fa  += lds_acc[w2][lane][sl];
      dpt += lds_acc[w2][lane][16 + j];
    }
    float v = fa / dpt;
    v = (v > 0.f) ? v : (__expf(v) - 1.f);
    v = (v > 0.f) ? v : (__expf(v) - 1.f);
    out[(size_t)(n0 + row_o) * KF + k * 64 + w4 * 16 + row] = v;
  }
}

// ---------- launcher ----------
extern "C" void kernel_launch(void* const* d_in, const int* in_sizes, int n_in,
                              void* d_out, int out_size, void* d_ws, size_t ws_size,
                              hipStream_t stream) {
  const float* x    = (const float*)d_in[0];   // (4096,256) fp32
  const float* Ww   = (const float*)d_in[1];   // (512,256)  fp32
  const float* Wb   = (const float*)d_in[2];   // (512,)     fp32
  const float* al   = (const float*)d_in[3];   // (1,8,64)   fp32
  const float* ar   = (const float*)d_in[4];   // (1,8,64)   fp32
  const int*   mask = (const int*)d_in[5];     // (1,4096,4096) int32

  float* out      = (float*)d_out;                    // (4096,512) fp32, 8 MB
  float* out_mask = out + (size_t)N_NODES * KF;       // (1,4096,4096) fp32, 64 MB

  const bool use_ws = (ws_size >= (8u << 20));
  char* scratch = use_ws ? (char*)d_ws : (char*)out_mask;
  unsigned short* xeB  = (unsigned short*)scratch;                 // 4 MB
  float*          hl   = (float*)(scratch + (4u << 20));           // 128 KB
  unsigned*       E12  = (unsigned*)(hl + KH * N_NODES);           // 128 KB
  float*          bmax = (float*)(E12 + KH * N_NODES);             // 2 KB
  unsigned long long* mbitsT = (unsigned long long*)(scratch + (5u << 20)); // 2 MB
  // top of use: 7 MB

  dim3 ga(N_NODES / 64, KF / 64);
  xe_gemm<<<ga, 256, 0, stream>>>(x, Ww, Wb, al, ar, xeB, hl, E12, bmax);

  if (use_ws) {
    mask_fused<<<(N_NODES * (size_t)N_NODES) / 1024, 256, 0, stream>>>(
        mask, out_mask, mbitsT);
    gat_attn<<<256 * KH, 256, 0, stream>>>(mbitsT, hl, bmax, E12, xeB, out);
  } else {
    mask_pack<<<(N_NODES * (size_t)N_NODES) / 256, 256, 0, stream>>>(mask, mbitsT);
    gat_attn<<<256 * KH, 256, 0, stream>>>(mbitsT, hl, bmax, E12, xeB, out);
    mask_copy<<<(N_NODES * (size_t)N_NODES) / (4 * 256), 256, 0, stream>>>(mask, out_mask);
  }
}

// Round 12
// 242.569 us; speedup vs baseline: 4.0783x; 1.0069x over previous
//
#include <hip/hip_runtime.h>
#include <hip/hip_bf16.h>

// Problem constants (GAT_18176301597437)
#define N_NODES 4096
#define F_IN    256
#define KH      8
#define KF      512          // KH*FPH
#define NEG_SLOPE 0.2f
#define EBIAS   4.0f

typedef _Float16 half8v __attribute__((ext_vector_type(8)));   // MFMA f16 A/B
typedef _Float16 half2v __attribute__((ext_vector_type(2)));   // packed f16 pair
typedef __attribute__((ext_vector_type(4))) float floatx4;     // MFMA C/D

union H8U4 { half8v v; unsigned u[4]; };

__device__ __forceinline__ unsigned short f2h(float f) {
    _Float16 h = (_Float16)f;
    unsigned short u; __builtin_memcpy(&u, &h, 2);
    return u;
}
__device__ __forceinline__ half2v asH2(unsigned u) {
    half2v h; __builtin_memcpy(&h, &u, 4);
    return h;
}
__device__ __forceinline__ unsigned asU(half2v h) {
    unsigned u; __builtin_memcpy(&u, &h, 4);
    return u;
}

// ---------- mask_fused: one pass -> fp32 passthrough + TRANSPOSED bit-pack ----
__global__ __launch_bounds__(256) void mask_fused(
    const int* __restrict__ mask, float* __restrict__ outm,
    unsigned long long* __restrict__ bits) {
  const size_t base = (size_t)blockIdx.x * 1024;
  const int tid = threadIdx.x;
  #pragma unroll
  for (int c = 0; c < 4; ++c) {
    const size_t e = base + c * 256 + tid;
    const int v = mask[e];
    outm[e] = v ? 1.f : 0.f;
    const unsigned long long b = __ballot(v != 0);
    if ((tid & 63) == 0) {
      const size_t w = e >> 6;
      bits[(w & 63) * (size_t)N_NODES + (w >> 6)] = b;
    }
  }
}

// ---------- fallback pair (scratch inside out_mask region) ----------
__global__ __launch_bounds__(256) void mask_pack(
    const int* __restrict__ mask, unsigned long long* __restrict__ bits) {
  const size_t idx = (size_t)blockIdx.x * 256 + threadIdx.x;
  const unsigned long long b = __ballot(mask[idx] != 0);
  if ((threadIdx.x & 63) == 0) {
    const size_t w = idx >> 6;
    bits[(w & 63) * (size_t)N_NODES + (w >> 6)] = b;
  }
}
__global__ __launch_bounds__(256) void mask_copy(
    const int* __restrict__ mask, float* __restrict__ outm) {
  const size_t i4 = (size_t)blockIdx.x * 256 + threadIdx.x;
  const int4 mv = ((const int4*)mask)[i4];
  float4 o;
  o.x = mv.x ? 1.f : 0.f; o.y = mv.y ? 1.f : 0.f;
  o.z = mv.z ? 1.f : 0.f; o.w = mv.w ? 1.f : 0.f;
  ((float4*)outm)[i4] = o;
}

// ---------- Kernel A: xe-GEMM + fused hl/EA/EB/blockmax epilogue -------------
// xeB tile = (head k, ft, chunk c): 1024 f16 = [h(2)][f(16)][quad(4)][j(8)].
// EA[k][n/2] = packed f16 pair exp(hr-4); EB = exp(0.2*(hr-4)).
__global__ __launch_bounds__(256) void xe_gemm(
    const float* __restrict__ x,
    const float* __restrict__ Ww,
    const float* __restrict__ Wb,
    const float* __restrict__ al,
    const float* __restrict__ ar,
    unsigned short* __restrict__ xeB,
    float* __restrict__ hl,             // [8][4096]
    unsigned* __restrict__ EA,          // [8][2048]
    unsigned* __restrict__ EB,          // [8][2048]
    float* __restrict__ bmax) {         // [8][64]
  __shared__ float As[32][65];
  __shared__ float Bs[32][65];
  __shared__ float redmax[4];
  const int tid = threadIdx.x;
  const int n0 = blockIdx.x * 64;
  const int j0 = blockIdx.y * 64;
  const int lr = tid >> 2;
  const int lc = (tid & 3) * 8;
  const int ty = tid >> 4;
  const int tx = tid & 15;
  float c[4][4];
  #pragma unroll
  for (int i = 0; i < 4; ++i)
    #pragma unroll
    for (int j = 0; j < 4; ++j) c[i][j] = 0.f;

  for (int f0 = 0; f0 < F_IN; f0 += 32) {
    const float* ap = x  + (size_t)(n0 + lr) * F_IN + f0 + lc;
    const float* bp = Ww + (size_t)(j0 + lr) * F_IN + f0 + lc;
    const float4 a0 = *(const float4*)ap;
    const float4 a1 = *(const float4*)(ap + 4);
    const float4 b0 = *(const float4*)bp;
    const float4 b1 = *(const float4*)(bp + 4);
    __syncthreads();
    As[lc + 0][lr] = a0.x; As[lc + 1][lr] = a0.y;
    As[lc + 2][lr] = a0.z; As[lc + 3][lr] = a0.w;
    As[lc + 4][lr] = a1.x; As[lc + 5][lr] = a1.y;
    As[lc + 6][lr] = a1.z; As[lc + 7][lr] = a1.w;
    Bs[lc + 0][lr] = b0.x; Bs[lc + 1][lr] = b0.y;
    Bs[lc + 2][lr] = b0.z; Bs[lc + 3][lr] = b0.w;
    Bs[lc + 4][lr] = b1.x; Bs[lc + 5][lr] = b1.y;
    Bs[lc + 6][lr] = b1.z; Bs[lc + 7][lr] = b1.w;
    __syncthreads();
    #pragma unroll
    for (int kk = 0; kk < 32; ++kk) {
      const float4 av = *(const float4*)&As[kk][ty * 4];
      const float4 bv = *(const float4*)&Bs[kk][tx * 4];
      const float a4[4] = {av.x, av.y, av.z, av.w};
      const float b4[4] = {bv.x, bv.y, bv.z, bv.w};
      #pragma unroll
      for (int i = 0; i < 4; ++i)
        #pragma unroll
        for (int j = 0; j < 4; ++j) c[i][j] = fmaf(a4[i], b4[j], c[i][j]);
    }
  }
  const float4 wb4 = *(const float4*)(Wb + j0 + tx * 4);
  const float4 al4 = *(const float4*)(al + j0 + tx * 4);
  const float4 ar4 = *(const float4*)(ar + j0 + tx * 4);
  const float wb[4] = {wb4.x, wb4.y, wb4.z, wb4.w};
  const float alv[4] = {al4.x, al4.y, al4.z, al4.w};
  const float arv[4] = {ar4.x, ar4.y, ar4.z, ar4.w};
  float v[4][4];
  float pl[4], pr[4];
  #pragma unroll
  for (int i = 0; i < 4; ++i) {
    float sl = 0.f, sr = 0.f;
    #pragma unroll
    for (int j = 0; j < 4; ++j) {
      v[i][j] = c[i][j] + wb[j];
      sl = fmaf(v[i][j], alv[j], sl);
      sr = fmaf(v[i][j], arv[j], sr);
    }
    pl[i] = sl; pr[i] = sr;
  }
  {
    const int k   = blockIdx.y;
    const int ft  = tx >> 2;
    const int fb  = (tx & 3) * 4;
    const int cc  = blockIdx.x;
    const int h_  = ty >> 3;
    const int qd  = (ty >> 1) & 3;
    const int jj0 = (ty & 1) * 4;
    unsigned short* tile = xeB + ((((size_t)(k * 4 + ft)) * 64 + cc) << 10)
                         + h_ * 512 + qd * 8 + jj0;
    #pragma unroll
    for (int j = 0; j < 4; ++j) {
      ushort4 pk;
      pk.x = f2h(v[0][j]); pk.y = f2h(v[1][j]);
      pk.z = f2h(v[2][j]); pk.w = f2h(v[3][j]);
      *(ushort4*)(tile + (fb + j) * 32) = pk;
    }
  }
  #pragma unroll
  for (int off = 8; off > 0; off >>= 1) {
    #pragma unroll
    for (int i = 0; i < 4; ++i) {
      pl[i] += __shfl_down(pl[i], off);
      pr[i] += __shfl_down(pr[i], off);
    }
  }
  if (tx == 0) {
    const int k = blockIdx.y;
    float4 o0 = {pl[0], pl[1], pl[2], pl[3]};
    *(float4*)(hl + k * N_NODES + n0 + ty * 4) = o0;
    // packed f16 pairs: EA = exp(hr-4), EB = exp(0.2*(hr-4))
    unsigned short e1[4], e2[4];
    #pragma unroll
    for (int i = 0; i < 4; ++i) {
      e1[i] = f2h(__expf(pr[i] - EBIAS));
      e2[i] = f2h(__expf(NEG_SLOPE * (pr[i] - EBIAS)));
    }
    uint2 wa, wbv;
    wa.x  = (unsigned)e1[0] | ((unsigned)e1[1] << 16);
    wa.y  = (unsigned)e1[2] | ((unsigned)e1[3] << 16);
    wbv.x = (unsigned)e2[0] | ((unsigned)e2[1] << 16);
    wbv.y = (unsigned)e2[2] | ((unsigned)e2[3] << 16);
    *(uint2*)(EA + k * 2048 + ((n0 + ty * 4) >> 1)) = wa;
    *(uint2*)(EB + k * 2048 + ((n0 + ty * 4) >> 1)) = wbv;
  }
  float bm = (tx == 0)
      ? fmaxf(fmaxf(pr[0], pr[1]), fmaxf(pr[2], pr[3])) : -1e30f;
  bm = fmaxf(bm, __shfl_xor(bm, 16));
  bm = fmaxf(bm, __shfl_xor(bm, 32));
  if ((tid & 63) == 0) redmax[tid >> 6] = bm;
  __syncthreads();
  if (tid == 0) {
    bmax[blockIdx.y * 64 + blockIdx.x] =
        fmaxf(fmaxf(redmax[0], redmax[1]), fmaxf(redmax[2], redmax[3]));
  }
}

// ---------- Kernel D: fused attention, packed-f16 w, software-pipelined ------
// Block = 256 thr = 4 waves = one (16-row group, head); wave = 16 m-chunks.
// w pair = max(c1*EA, c2*EB) via native _Float16 vector ops (v_pk_mul_f16 /
// v_pk_max_f16); mask applied as AND-mask built with shift/or/mul.
__global__ __launch_bounds__(256, 4) void gat_attn(
    const unsigned long long* __restrict__ mbitsT,   // [64 c][4096 n]
    const float* __restrict__ hl,
    const float* __restrict__ bmax,                  // [8][64]
    const unsigned* __restrict__ EA,                 // [8][2048] f16 pairs
    const unsigned* __restrict__ EB,
    const unsigned short* __restrict__ xeB,          // f16 frag tiles
    float* __restrict__ out) {
  __shared__ float lds_acc[4][64][20];   // 20 KB
  const int t = threadIdx.x;
  const int w4 = t >> 6;                // wave 0..3 = m-quarter
  const int lane = t & 63;
  const int k  = blockIdx.x >> 8;       // same-k grouping for L2 locality
  const int rg = blockIdx.x & 255;
  const int n0 = rg * 16;
  const int row = lane & 15;
  const int quad = lane >> 4;
  const int q8 = quad * 8;

  float hm = bmax[k * 64 + lane];
  #pragma unroll
  for (int o = 1; o < 64; o <<= 1) hm = fmaxf(hm, __shfl_xor(hm, o));

  const float hlv = hl[k * N_NODES + n0 + row];
  const float sM = hlv + hm;
  const float Mv = fmaxf(sM, NEG_SLOPE * sM);
  const float c1f = __expf(hlv + EBIAS - Mv);               // w_pos = c1*EA
  const float c2f = __expf(NEG_SLOPE * (hlv + EBIAS) - Mv); // w_neg = c2*EB
  const half2v c1h2 = {(_Float16)c1f, (_Float16)c1f};
  const half2v c2h2 = {(_Float16)c2f, (_Float16)c2f};

  const int c0 = w4 * 16;
  const int cEnd = c0 + 16;

  // running pointers (incremented per chunk)
  const unsigned* pEA = EA + k * 2048 + c0 * 32 + quad * 4;
  const unsigned* pEB = EB + k * 2048 + c0 * 32 + quad * 4;
  const unsigned long long* pM = mbitsT + (size_t)c0 * N_NODES + n0 + row;
  const unsigned short* pB = xeB + (((size_t)k * 4) << 16)
                           + ((size_t)c0 << 10) + row * 32 + q8;

  half8v ones;
  #pragma unroll
  for (int i = 0; i < 8; ++i) ones[i] = (_Float16)1.0f;

  floatx4 acc[4];
  #pragma unroll
  for (int ft = 0; ft < 4; ++ft) acc[ft] = (floatx4){0.f, 0.f, 0.f, 0.f};
  floatx4 accdp = (floatx4){0.f, 0.f, 0.f, 0.f};

  // prefetch chunk c0: EA lo/hi, EB lo/hi, mask word
  uint4 pA0 = *(const uint4*)pEA;
  uint4 pA1 = *(const uint4*)(pEA + 16);
  uint4 pB0 = *(const uint4*)pEB;
  uint4 pB1 = *(const uint4*)(pEB + 16);
  unsigned long long pMv = *pM;

  for (int cc = c0; cc < cEnd; ++cc) {
    // ---- issue B loads for this chunk ----
    half8v b0, b1, b2, b3, b4, b5, b6, b7;
    b0 = *(const half8v*)pB;                     b1 = *(const half8v*)(pB + 512);
    b2 = *(const half8v*)(pB + (64 << 10));      b3 = *(const half8v*)(pB + (64 << 10) + 512);
    b4 = *(const half8v*)(pB + (128 << 10));     b5 = *(const half8v*)(pB + (128 << 10) + 512);
    b6 = *(const half8v*)(pB + (192 << 10));     b7 = *(const half8v*)(pB + (192 << 10) + 512);
    pB += 1024;
    // ---- stash current E/mask, prefetch next ----
    const uint4 eA0 = pA0, eA1 = pA1, eB0 = pB0, eB1 = pB1;
    const unsigned long long mb = pMv;
    pEA += 32; pEB += 32; pM += N_NODES;
    if (cc + 1 < cEnd) {
      pA0 = *(const uint4*)pEA;
      pA1 = *(const uint4*)(pEA + 16);
      pB0 = *(const uint4*)pEB;
      pB1 = *(const uint4*)(pEB + 16);
      pMv = *pM;
    }
    // ---- w-compute (packed f16, native vector ops) ----
    const unsigned mlo = (unsigned)(mb >> q8);
    const unsigned mhi = (unsigned)(mb >> (32 + q8));
    H8U4 a0, a1;
    {
      const unsigned ea[4] = {eA0.x, eA0.y, eA0.z, eA0.w};
      const unsigned eb[4] = {eB0.x, eB0.y, eB0.z, eB0.w};
      #pragma unroll
      for (int p = 0; p < 4; ++p) {
        const half2v w2 = __builtin_elementwise_max(c1h2 * asH2(ea[p]),
                                                    c2h2 * asH2(eb[p]));
        const unsigned tb = mlo >> (2 * p);
        const unsigned sel = (((tb & 1u) | ((tb & 2u) << 15)) * 0xFFFFu);
        a0.u[p] = asU(w2) & sel;
      }
    }
    {
      const unsigned ea[4] = {eA1.x, eA1.y, eA1.z, eA1.w};
      const unsigned eb[4] = {eB1.x, eB1.y, eB1.z, eB1.w};
      #pragma unroll
      for (int p = 0; p < 4; ++p) {
        const half2v w2 = __builtin_elementwise_max(c1h2 * asH2(ea[p]),
                                                    c2h2 * asH2(eb[p]));
        const unsigned tb = mhi >> (2 * p);
        const unsigned sel = (((tb & 1u) | ((tb & 2u) << 15)) * 0xFFFFu);
        a1.u[p] = asU(w2) & sel;
      }
    }
    // ---- MFMAs (f16) ----
    accdp = __builtin_amdgcn_mfma_f32_16x16x32_f16(a0.v, ones, accdp, 0, 0, 0);
    accdp = __builtin_amdgcn_mfma_f32_16x16x32_f16(a1.v, ones, accdp, 0, 0, 0);
    acc[0] = __builtin_amdgcn_mfma_f32_16x16x32_f16(a0.v, b0, acc[0], 0, 0, 0);
    acc[0] = __builtin_amdgcn_mfma_f32_16x16x32_f16(a1.v, b1, acc[0], 0, 0, 0);
    acc[1] = __builtin_amdgcn_mfma_f32_16x16x32_f16(a0.v, b2, acc[1], 0, 0, 0);
    acc[1] = __builtin_amdgcn_mfma_f32_16x16x32_f16(a1.v, b3, acc[1], 0, 0, 0);
    acc[2] = __builtin_amdgcn_mfma_f32_16x16x32_f16(a0.v, b4, acc[2], 0, 0, 0);
    acc[2] = __builtin_amdgcn_mfma_f32_16x16x32_f16(a1.v, b5, acc[2], 0, 0, 0);
    acc[3] = __builtin_amdgcn_mfma_f32_16x16x32_f16(a0.v, b6, acc[3], 0, 0, 0);
    acc[3] = __builtin_amdgcn_mfma_f32_16x16x32_f16(a1.v, b7, acc[3], 0, 0, 0);
  }

  // write partials (16 C slots + 4 dp slots per lane)
  #pragma unroll
  for (int i = 0; i < 16; ++i) lds_acc[w4][lane][i] = acc[i >> 2][i & 3];
  #pragma unroll
  for (int i = 0; i < 4; ++i) lds_acc[w4][lane][16 + i] = accdp[i];
  __syncthreads();

  // wave w4 finalizes ft = w4 (slots 4*w4 .. +3; reg j -> row quad*4+j)
  #pragma unroll
  for (int j = 0; j < 4; ++j) {
    const int sl = 4 * w4 + j;
    const int row_o = quad * 4 + j;
    float fa = 0.f, dpt = 0.f;
    #pragma unroll
    for (int w2 = 0; w2 < 4; ++w2) {
      fa  += lds_acc[w2][lane][sl];
      dpt += lds_acc[w2][lane][16 + j];
    }
    float v = fa / dpt;
    v = (v > 0.f) ? v : (__expf(v) - 1.f);
    v = (v > 0.f) ? v : (__expf(v) - 1.f);
    out[(size_t)(n0 + row_o) * KF + k * 64 + w4 * 16 + row] = v;
  }
}

// ---------- launcher ----------
extern "C" void kernel_launch(void* const* d_in, const int* in_sizes, int n_in,
                              void* d_out, int out_size, void* d_ws, size_t ws_size,
                              hipStream_t stream) {
  const float* x    = (const float*)d_in[0];   // (4096,256) fp32
  const float* Ww   = (const float*)d_in[1];   // (512,256)  fp32
  const float* Wb   = (const float*)d_in[2];   // (512,)     fp32
  const float* al   = (const float*)d_in[3];   // (1,8,64)   fp32
  const float* ar   = (const float*)d_in[4];   // (1,8,64)   fp32
  const int*   mask = (const int*)d_in[5];     // (1,4096,4096) int32

  float* out      = (float*)d_out;                    // (4096,512) fp32, 8 MB
  float* out_mask = out + (size_t)N_NODES * KF;       // (1,4096,4096) fp32, 64 MB

  const bool use_ws = (ws_size >= (8u << 20));
  char* scratch = use_ws ? (char*)d_ws : (char*)out_mask;
  unsigned short* xeB  = (unsigned short*)scratch;                 // 4 MB
  float*          hl   = (float*)(scratch + (4u << 20));           // 128 KB
  unsigned*       EA   = (unsigned*)(hl + KH * N_NODES);           // 64 KB
  unsigned*       EB   = EA + KH * 2048;                           // 64 KB
  float*          bmax = (float*)(EB + KH * 2048);                 // 2 KB
  unsigned long long* mbitsT = (unsigned long long*)(scratch + (5u << 20)); // 2 MB
  // top of use: 7 MB

  dim3 ga(N_NODES / 64, KF / 64);
  xe_gemm<<<ga, 256, 0, stream>>>(x, Ww, Wb, al, ar, xeB, hl, EA, EB, bmax);

  if (use_ws) {
    mask_fused<<<(N_NODES * (size_t)N_NODES) / 1024, 256, 0, stream>>>(
        mask, out_mask, mbitsT);
    gat_attn<<<256 * KH, 256, 0, stream>>>(mbitsT, hl, bmax, EA, EB, xeB, out);
  } else {
    mask_pack<<<(N_NODES * (size_t)N_NODES) / 256, 256, 0, stream>>>(mask, mbitsT);
    gat_attn<<<256 * KH, 256, 0, stream>>>(mbitsT, hl, bmax, EA, EB, xeB, out);
    mask_copy<<<(N_NODES * (size_t)N_NODES) / (4 * 256), 256, 0, stream>>>(mask, out_mask);
  }
}